// Round 2
// baseline (1135.332 us; speedup 1.0000x reference)
//
#include <hip/hip_runtime.h>
#include <stdint.h>

typedef unsigned short u16;
typedef short bf16x8 __attribute__((ext_vector_type(8)));
typedef float f32x4 __attribute__((ext_vector_type(4)));
typedef u16 u16x4 __attribute__((ext_vector_type(4)));

__device__ __forceinline__ u16 f2bf(float f) {
    unsigned u = __builtin_bit_cast(unsigned, f);
    unsigned r = (u + 0x7fffu + ((u >> 16) & 1u)) >> 16;
    return (u16)r;
}
__device__ __forceinline__ float bf2f(u16 h) {
    unsigned u = ((unsigned)h) << 16;
    return __builtin_bit_cast(float, u);
}

typedef const __attribute__((address_space(1))) unsigned int* gptr_t;
typedef __attribute__((address_space(3))) unsigned int* lptr_t;
__device__ __forceinline__ void gload16(const void* g, void* l) {
    __builtin_amdgcn_global_load_lds((gptr_t)(uintptr_t)g, (lptr_t)(uintptr_t)l, 16, 0, 0);
}

// ---------------- cast f32 -> bf16 (vectorized) ----------------
__global__ __launch_bounds__(256) void cast_bf16(const float4* __restrict__ in,
                                                 u16x4* __restrict__ out, int n4) {
    int i = blockIdx.x * 256 + threadIdx.x;
    if (i < n4) {
        float4 f = in[i];
        u16x4 o = {f2bf(f.x), f2bf(f.y), f2bf(f.z), f2bf(f.w)};
        out[i] = o;
    }
}

// ---------------- NT GEMM: C[m,n] = alpha * sum_k A[m,k]*B[n,k] ----------------
// A: [M,K] bf16 row-major (lda), B: [N,K] bf16 row-major (ldb), batched over z
// z -> (bb = z/hdiv, hh = z%hdiv); per-operand strides for bb and hh.
// BM=BN=64, BK=64, 256 threads (4 waves), wave computes 32x32 via 2x2 MFMA frags.
template <typename OUT>
__global__ __launch_bounds__(256) void gemm_nt(
    const u16* __restrict__ A, long sAb, long sAh, int lda,
    const u16* __restrict__ B, long sBb, long sBh, int ldb,
    OUT* __restrict__ C, long sCz, int ldc,
    int M, int N, int K, int hdiv, float alpha) {
    __shared__ u16 sA[64 * 64];
    __shared__ u16 sB[64 * 64];
    int z = blockIdx.z, bb = z / hdiv, hh = z - bb * hdiv;
    const u16* Ab = A + (size_t)bb * sAb + (size_t)hh * sAh;
    const u16* Bb = B + (size_t)bb * sBb + (size_t)hh * sBh;
    OUT* Cb = C + (size_t)z * sCz;
    int tm = blockIdx.y * 64, tn = blockIdx.x * 64;
    int t = threadIdx.x, lane = t & 63, w = t >> 6;
    int wr = w >> 1, wc = w & 1;
    int srow = t >> 3, scol = (t & 7) * 8;
    const u16* ga = Ab + (size_t)(tm + srow) * lda + scol;
    const u16* gb = Bb + (size_t)(tn + srow) * ldb + scol;
    f32x4 acc[2][2] = {};
    int la = lane & 15, lk = (lane >> 4) * 8;
    for (int k0 = 0; k0 < K; k0 += 64) {
        gload16(ga, &sA[t * 8]);
        gload16(ga + 32 * lda, &sA[t * 8 + 2048]);
        gload16(gb, &sB[t * 8]);
        gload16(gb + 32 * ldb, &sB[t * 8 + 2048]);
        ga += 64;
        gb += 64;
        __syncthreads();
#pragma unroll
        for (int kk = 0; kk < 64; kk += 32) {
            bf16x8 a0 = *(const bf16x8*)&sA[(wr * 32 + la) * 64 + kk + lk];
            bf16x8 a1 = *(const bf16x8*)&sA[(wr * 32 + 16 + la) * 64 + kk + lk];
            bf16x8 b0 = *(const bf16x8*)&sB[(wc * 32 + la) * 64 + kk + lk];
            bf16x8 b1 = *(const bf16x8*)&sB[(wc * 32 + 16 + la) * 64 + kk + lk];
            acc[0][0] = __builtin_amdgcn_mfma_f32_16x16x32_bf16(a0, b0, acc[0][0], 0, 0, 0);
            acc[0][1] = __builtin_amdgcn_mfma_f32_16x16x32_bf16(a0, b1, acc[0][1], 0, 0, 0);
            acc[1][0] = __builtin_amdgcn_mfma_f32_16x16x32_bf16(a1, b0, acc[1][0], 0, 0, 0);
            acc[1][1] = __builtin_amdgcn_mfma_f32_16x16x32_bf16(a1, b1, acc[1][1], 0, 0, 0);
        }
        __syncthreads();
    }
#pragma unroll
    for (int mi = 0; mi < 2; mi++)
#pragma unroll
        for (int ni = 0; ni < 2; ni++)
#pragma unroll
            for (int r = 0; r < 4; r++) {
                int m = tm + wr * 32 + mi * 16 + (lane >> 4) * 4 + r;
                int n = tn + wc * 32 + ni * 16 + (lane & 15);
                float v = acc[mi][ni][r] * alpha;
                if constexpr (sizeof(OUT) == 4)
                    Cb[(size_t)m * ldc + n] = v;
                else
                    Cb[(size_t)m * ldc + n] = f2bf(v);
            }
}

// ---------------- instance-norm stats per (b,h) plane ----------------
__global__ __launch_bounds__(256) void in_stats(const float* __restrict__ sc,
                                                float* __restrict__ stats, int cnt) {
    int z = blockIdx.x;
    const float4* p = (const float4*)(sc + (size_t)z * cnt);
    int n4 = cnt >> 2;
    double s = 0.0, q = 0.0;
    for (int i = threadIdx.x; i < n4; i += 256) {
        float4 f = p[i];
        s += (double)f.x + f.y + f.z + f.w;
        q += (double)f.x * f.x + (double)f.y * f.y + (double)f.z * f.z + (double)f.w * f.w;
    }
#pragma unroll
    for (int o = 32; o; o >>= 1) {
        s += __shfl_down(s, o);
        q += __shfl_down(q, o);
    }
    __shared__ double rs[4], rq[4];
    int w = threadIdx.x >> 6;
    if ((threadIdx.x & 63) == 0) {
        rs[w] = s;
        rq[w] = q;
    }
    __syncthreads();
    if (threadIdx.x == 0) {
        double S = rs[0] + rs[1] + rs[2] + rs[3];
        double Q = rq[0] + rq[1] + rq[2] + rq[3];
        float mu = (float)(S / cnt);
        float var = (float)(Q / cnt) - mu * mu;
        stats[2 * z] = mu;
        stats[2 * z + 1] = rsqrtf(var + 1e-5f);
    }
}

// ---------------- normalize + row softmax (row length 960), write bf16 ----------------
__global__ __launch_bounds__(256) void norm_softmax(const float* __restrict__ sc,
                                                    const float* __restrict__ stats,
                                                    u16* __restrict__ pr, int C) {
    int row = blockIdx.x;
    int z = row / C;
    const float* x = sc + (size_t)row * 960;
    u16* o = pr + (size_t)row * 960;
    float mu = stats[2 * z], rs = stats[2 * z + 1];
    int t = threadIdx.x;
    float v[4];
    float mx = -1e30f;
#pragma unroll
    for (int j = 0; j < 4; j++) {
        int i = j * 256 + t;
        if (i < 960) {
            float y = (x[i] - mu) * rs;
            v[j] = y;
            mx = fmaxf(mx, y);
        } else
            v[j] = -1e30f;
    }
    __shared__ float r1[4], r2[4];
#pragma unroll
    for (int o_ = 32; o_; o_ >>= 1) mx = fmaxf(mx, __shfl_xor(mx, o_));
    int w = t >> 6;
    if ((t & 63) == 0) r1[w] = mx;
    __syncthreads();
    mx = fmaxf(fmaxf(r1[0], r1[1]), fmaxf(r1[2], r1[3]));
    float s = 0.f;
#pragma unroll
    for (int j = 0; j < 4; j++) {
        int i = j * 256 + t;
        if (i < 960) {
            v[j] = __expf(v[j] - mx);
            s += v[j];
        }
    }
#pragma unroll
    for (int o_ = 32; o_; o_ >>= 1) s += __shfl_xor(s, o_);
    if ((t & 63) == 0) r2[w] = s;
    __syncthreads();
    s = r2[0] + r2[1] + r2[2] + r2[3];
    float inv = 1.0f / s;
#pragma unroll
    for (int j = 0; j < 4; j++) {
        int i = j * 256 + t;
        if (i < 960) o[i] = f2bf(v[j] * inv);
    }
}

// ---------------- head-mean + transpose: cm[b][n][c] = mean_h ctx[b*4+h][c][n] ----------------
__global__ __launch_bounds__(256) void mean_heads(const u16* __restrict__ ctx,
                                                  u16* __restrict__ cm, int C) {
    int b = blockIdx.z;
    int n0 = blockIdx.x * 64, c0 = blockIdx.y * 64;
    __shared__ float sm[64][65];
    int t = threadIdx.x;
    float acc[16];
#pragma unroll
    for (int j = 0; j < 16; j++) acc[j] = 0.f;
    for (int h = 0; h < 4; h++) {
        const u16* p = ctx + (size_t)(b * 4 + h) * C * 1024;
#pragma unroll
        for (int j = 0; j < 16; j++) {
            int lin = j * 256 + t;
            int cc = lin >> 6, nn = lin & 63;
            acc[j] += bf2f(p[(size_t)(c0 + cc) * 1024 + n0 + nn]);
        }
    }
#pragma unroll
    for (int j = 0; j < 16; j++) {
        int lin = j * 256 + t;
        sm[lin >> 6][lin & 63] = acc[j] * 0.25f;
    }
    __syncthreads();
#pragma unroll
    for (int j = 0; j < 16; j++) {
        int lin = j * 256 + t;
        int nn = lin >> 6, cc = lin & 63;
        cm[((size_t)b * 1024 + n0 + nn) * C + c0 + cc] = f2bf(sm[cc][nn]);
    }
}

extern "C" void kernel_launch(void* const* d_in, const int* in_sizes, int n_in,
                              void* d_out, int out_size, void* d_ws, size_t ws_size,
                              hipStream_t stream) {
    const int B = 8, NN = 1024, KV = 960;
    const int Cs[4] = {64, 128, 256, 512};
    const float* emb[4];
    for (int i = 0; i < 4; i++) emb[i] = (const float*)d_in[i];
    const float* embAll = (const float*)d_in[4];
    const float* Wq[4];
    for (int i = 0; i < 4; i++) Wq[i] = (const float*)d_in[5 + i];
    const float* Wk = (const float*)d_in[9];
    const float* Wv = (const float*)d_in[10];
    const float* Wo[4];
    for (int i = 0; i < 4; i++) Wo[i] = (const float*)d_in[11 + i];
    float* out = (float*)d_out;

    // ---- workspace layout (aliased; total ~234 MB) ----
    // buf1 (63MB): {eA, wk, wv} during init -> sc (f32) -> ctx (bf16), per branch
    // buf2 (33.5MB): Qt -> pr
    // Kt, Vb (63MB each) resident; wq/wo small resident; cmX (8.4MB): eI_i -> cm
    const size_t S1 = 62914560, S2 = 33554432, SKV = 62914560;
    const size_t SWQ = 2785280, SWO = 696320, SCM = 8388608;
    const size_t NEED = S1 + S2 + 2 * SKV + SWQ + SWO + SCM + 256;
    if (ws_size < NEED) return;  // deterministic no-op -> diagnosable as ws-too-small

    char* base = (char*)d_ws;
    char* buf1 = base;
    char* buf2 = buf1 + S1;
    u16* Kt = (u16*)(buf2 + S2);              // [z][j=960][n=1024]
    u16* Vb = (u16*)((char*)Kt + SKV);        // [z][n=1024][j=960]
    char* pw = (char*)Vb + SKV;
    u16* wq[4];
    for (int i = 0; i < 4; i++) {
        wq[i] = (u16*)pw;
        pw += (size_t)4 * Cs[i] * Cs[i] * 2;
    }
    u16* wo[4];
    for (int i = 0; i < 4; i++) {
        wo[i] = (u16*)pw;
        pw += (size_t)Cs[i] * Cs[i] * 2;
    }
    u16* cmX = (u16*)pw;  // eI_i (branch input cast) then cm (head-mean out)
    pw += SCM;
    float* stats = (float*)pw;

    // aliases inside buf1/buf2
    u16* eA = (u16*)buf1;                       // 15,728,640 B
    u16* wk = (u16*)(buf1 + 15728640);          // 7,372,800 B
    u16* wv = (u16*)(buf1 + 23101440);          // 7,372,800 B (ends 30.5MB < S1)
    float* sc = (float*)buf1;                   // per-branch scores f32
    u16* ctx = (u16*)buf1;                      // per-branch ctx bf16
    u16* Qt = (u16*)buf2;
    u16* pr = (u16*)buf2;

    auto castL = [&](const float* s, u16* d, size_t n) {
        int n4 = (int)(n / 4);
        int grid = (n4 + 255) / 256;
        cast_bf16<<<grid, 256, 0, stream>>>((const float4*)s, (u16x4*)d, n4);
    };
    castL(embAll, eA, (size_t)B * NN * KV);
    castL(Wk, wk, (size_t)4 * KV * KV);
    castL(Wv, wv, (size_t)4 * KV * KV);
    for (int i = 0; i < 4; i++) castL(Wq[i], wq[i], (size_t)4 * Cs[i] * Cs[i]);
    for (int i = 0; i < 4; i++) castL(Wo[i], wo[i], (size_t)Cs[i] * Cs[i]);

    float invs = 1.0f / sqrtf((float)KV);

    // Kt[z][j][n] = sum_k Wk[h][j][k] * embAll[b][n][k]
    gemm_nt<u16><<<dim3(NN / 64, KV / 64, 32), 256, 0, stream>>>(
        wk, 0, (long)KV * KV, KV, eA, (long)NN * KV, 0, KV, Kt, (long)KV * NN, NN,
        KV, NN, KV, 4, 1.0f);
    // Vb[z][n][j] = sum_k embAll[b][n][k] * Wv[h][j][k]
    gemm_nt<u16><<<dim3(KV / 64, NN / 64, 32), 256, 0, stream>>>(
        eA, (long)NN * KV, 0, KV, wv, 0, (long)KV * KV, KV, Vb, (long)NN * KV, KV,
        NN, KV, KV, 4, 1.0f);

    size_t off = 0;
    for (int i = 0; i < 4; i++) {
        int C = Cs[i];
        // branch input cast: emb_i -> cmX (bf16) [eA/wk/wv region free after this branch's QK overwrite]
        castL(emb[i], cmX, (size_t)B * NN * C);
        // Qt[z][c][n] = sum_d Wq[h][c][d] * emb_i[b][n][d]
        gemm_nt<u16><<<dim3(NN / 64, C / 64, 32), 256, 0, stream>>>(
            wq[i], 0, (long)C * C, C, cmX, (long)NN * C, 0, C, Qt, (long)C * NN,
            NN, C, NN, C, 4, 1.0f);
        // sc[z][c][k] = invs * sum_n Qt[z][c][n] * Kt[z][k][n]   (overwrites eA/wk/wv - dead)
        gemm_nt<float><<<dim3(KV / 64, C / 64, 32), 256, 0, stream>>>(
            Qt, 4L * C * NN, (long)C * NN, NN, Kt, 4L * KV * NN, (long)KV * NN, NN,
            sc, (long)C * KV, KV, C, KV, NN, 4, invs);
        // instance-norm stats over each [C,960] plane
        in_stats<<<32, 256, 0, stream>>>(sc, stats, C * KV);
        // normalize + softmax rows -> bf16 probs (overwrites Qt - dead)
        norm_softmax<<<32 * C, 256, 0, stream>>>(sc, stats, pr, C);
        // ctx[z][c][n] = sum_k pr[z][c][k] * Vb[z][n][k]   (overwrites sc - dead)
        gemm_nt<u16><<<dim3(NN / 64, C / 64, 32), 256, 0, stream>>>(
            pr, 4L * C * KV, (long)C * KV, KV, Vb, 4L * NN * KV, (long)NN * KV, KV,
            ctx, (long)C * NN, NN, C, NN, KV, 4, 1.0f);
        // head-mean + transpose -> cm[b][n][c] bf16 (overwrites eI_i - dead)
        mean_heads<<<dim3(NN / 64, C / 64, B), 256, 0, stream>>>(ctx, cmX, C);
        // out[b][n][c] = sum_d cm[b][n][d] * Wo[c][d]
        gemm_nt<float><<<dim3(C / 64, NN / 64, B), 256, 0, stream>>>(
            cmX, (long)NN * C, 0, C, wo[i], 0, 0, C, out + off, (long)NN * C, C,
            NN, C, C, 1, 1.0f);
        off += (size_t)B * NN * C;
    }
}

// Round 3
// 1030.560 us; speedup vs baseline: 1.1017x; 1.1017x over previous
//
#include <hip/hip_runtime.h>
#include <stdint.h>

typedef unsigned short u16;
typedef short bf16x8 __attribute__((ext_vector_type(8)));
typedef float f32x4 __attribute__((ext_vector_type(4)));
typedef u16 u16x4 __attribute__((ext_vector_type(4)));

__device__ __forceinline__ u16 f2bf(float f) {
    unsigned u = __builtin_bit_cast(unsigned, f);
    unsigned r = (u + 0x7fffu + ((u >> 16) & 1u)) >> 16;
    return (u16)r;
}
__device__ __forceinline__ float bf2f(u16 h) {
    unsigned u = ((unsigned)h) << 16;
    return __builtin_bit_cast(float, u);
}

typedef const __attribute__((address_space(1))) unsigned int* gptr_t;
typedef __attribute__((address_space(3))) unsigned int* lptr_t;
__device__ __forceinline__ void gload16(const void* g, void* l) {
    __builtin_amdgcn_global_load_lds((gptr_t)(uintptr_t)g, (lptr_t)(uintptr_t)l, 16, 0, 0);
}

// ---------------- cast f32 -> bf16 (vectorized) ----------------
__global__ __launch_bounds__(256) void cast_bf16(const float4* __restrict__ in,
                                                 u16x4* __restrict__ out, int n4) {
    int i = blockIdx.x * 256 + threadIdx.x;
    if (i < n4) {
        float4 f = in[i];
        u16x4 o = {f2bf(f.x), f2bf(f.y), f2bf(f.z), f2bf(f.w)};
        out[i] = o;
    }
}

// ---------------- NT GEMM (m97 structure): C[m,n] = alpha * sum_k A[m,k]*B[n,k] ----------------
// A: [M,K] bf16 row-major (lda), B: [N,K] bf16 row-major (ldb), batched over z
// z -> (bb = z/hdiv, hh = z%hdiv); per-operand strides for bb and hh.
// BM=BN=128, BK=64, 256 threads (4 waves in 2x2), wave computes 64x64 via 4x4 MFMA frags.
// Edge tiles: staging rows clamped to [0,M-1]/[0,N-1], C-writes guarded.
template <typename OUT>
__global__ __launch_bounds__(256) void gemm_nt128(
    const u16* __restrict__ A, long sAb, long sAh, int lda,
    const u16* __restrict__ B, long sBb, long sBh, int ldb,
    OUT* __restrict__ C, long sCz, int ldc,
    int M, int N, int K, int hdiv, float alpha) {
    __shared__ u16 sA[128 * 64];
    __shared__ u16 sB[128 * 64];
    int z = blockIdx.z, bb = z / hdiv, hh = z - bb * hdiv;
    const u16* Ab = A + (size_t)bb * sAb + (size_t)hh * sAh;
    const u16* Bb = B + (size_t)bb * sBb + (size_t)hh * sBh;
    OUT* Cb = C + (size_t)z * sCz;
    int tm = blockIdx.y * 128, tn = blockIdx.x * 128;
    int t = threadIdx.x, lane = t & 63, w = t >> 6;
    int wr = w >> 1, wc = w & 1;
    // staging: linear seg s = i*256+t -> LDS offset s*16B (wave-uniform base + lane*16)
    int r0 = t >> 3, c0 = (t & 7) * 8;
    f32x4 acc[4][4] = {};
    int la = lane & 15, lk = (lane >> 4) * 8;
    for (int k0 = 0; k0 < K; k0 += 64) {
#pragma unroll
        for (int i = 0; i < 4; i++) {
            int ar = tm + i * 32 + r0;
            if (ar > M - 1) ar = M - 1;
            gload16(Ab + (size_t)ar * lda + k0 + c0, &sA[(i * 256 + t) * 8]);
        }
#pragma unroll
        for (int i = 0; i < 4; i++) {
            int br = tn + i * 32 + r0;
            if (br > N - 1) br = N - 1;
            gload16(Bb + (size_t)br * ldb + k0 + c0, &sB[(i * 256 + t) * 8]);
        }
        __syncthreads();
#pragma unroll
        for (int kk = 0; kk < 64; kk += 32) {
            bf16x8 a[4], b[4];
#pragma unroll
            for (int mi = 0; mi < 4; mi++)
                a[mi] = *(const bf16x8*)&sA[(wr * 64 + mi * 16 + la) * 64 + kk + lk];
#pragma unroll
            for (int ni = 0; ni < 4; ni++)
                b[ni] = *(const bf16x8*)&sB[(wc * 64 + ni * 16 + la) * 64 + kk + lk];
#pragma unroll
            for (int mi = 0; mi < 4; mi++)
#pragma unroll
                for (int ni = 0; ni < 4; ni++)
                    acc[mi][ni] = __builtin_amdgcn_mfma_f32_16x16x32_bf16(
                        a[mi], b[ni], acc[mi][ni], 0, 0, 0);
        }
        __syncthreads();
    }
#pragma unroll
    for (int mi = 0; mi < 4; mi++)
#pragma unroll
        for (int ni = 0; ni < 4; ni++)
#pragma unroll
            for (int r = 0; r < 4; r++) {
                int m = tm + wr * 64 + mi * 16 + (lane >> 4) * 4 + r;
                int n = tn + wc * 64 + ni * 16 + la;
                if (m < M && n < N) {
                    float v = acc[mi][ni][r] * alpha;
                    if constexpr (sizeof(OUT) == 4)
                        Cb[(size_t)m * ldc + n] = v;
                    else
                        Cb[(size_t)m * ldc + n] = f2bf(v);
                }
            }
}

// ---------------- instance-norm stats per (b,h) plane ----------------
__global__ __launch_bounds__(256) void in_stats(const float* __restrict__ sc,
                                                float* __restrict__ stats, int cnt) {
    int z = blockIdx.x;
    const float4* p = (const float4*)(sc + (size_t)z * cnt);
    int n4 = cnt >> 2;
    double s = 0.0, q = 0.0;
    for (int i = threadIdx.x; i < n4; i += 256) {
        float4 f = p[i];
        s += (double)f.x + f.y + f.z + f.w;
        q += (double)f.x * f.x + (double)f.y * f.y + (double)f.z * f.z + (double)f.w * f.w;
    }
#pragma unroll
    for (int o = 32; o; o >>= 1) {
        s += __shfl_down(s, o);
        q += __shfl_down(q, o);
    }
    __shared__ double rs[4], rq[4];
    int w = threadIdx.x >> 6;
    if ((threadIdx.x & 63) == 0) {
        rs[w] = s;
        rq[w] = q;
    }
    __syncthreads();
    if (threadIdx.x == 0) {
        double S = rs[0] + rs[1] + rs[2] + rs[3];
        double Q = rq[0] + rq[1] + rq[2] + rq[3];
        float mu = (float)(S / cnt);
        float var = (float)(Q / cnt) - mu * mu;
        stats[2 * z] = mu;
        stats[2 * z + 1] = rsqrtf(var + 1e-5f);
    }
}

// ---------------- normalize + row softmax (row length 960), write bf16 ----------------
__global__ __launch_bounds__(256) void norm_softmax(const float* __restrict__ sc,
                                                    const float* __restrict__ stats,
                                                    u16* __restrict__ pr, int C) {
    int row = blockIdx.x;
    int z = row / C;
    const float* x = sc + (size_t)row * 960;
    u16* o = pr + (size_t)row * 960;
    float mu = stats[2 * z], rs = stats[2 * z + 1];
    int t = threadIdx.x;
    float v[4];
    float mx = -1e30f;
#pragma unroll
    for (int j = 0; j < 4; j++) {
        int i = j * 256 + t;
        if (i < 960) {
            float y = (x[i] - mu) * rs;
            v[j] = y;
            mx = fmaxf(mx, y);
        } else
            v[j] = -1e30f;
    }
    __shared__ float r1[4], r2[4];
#pragma unroll
    for (int o_ = 32; o_; o_ >>= 1) mx = fmaxf(mx, __shfl_xor(mx, o_));
    int w = t >> 6;
    if ((t & 63) == 0) r1[w] = mx;
    __syncthreads();
    mx = fmaxf(fmaxf(r1[0], r1[1]), fmaxf(r1[2], r1[3]));
    float s = 0.f;
#pragma unroll
    for (int j = 0; j < 4; j++) {
        int i = j * 256 + t;
        if (i < 960) {
            v[j] = __expf(v[j] - mx);
            s += v[j];
        }
    }
#pragma unroll
    for (int o_ = 32; o_; o_ >>= 1) s += __shfl_xor(s, o_);
    if ((t & 63) == 0) r2[w] = s;
    __syncthreads();
    s = r2[0] + r2[1] + r2[2] + r2[3];
    float inv = 1.0f / s;
#pragma unroll
    for (int j = 0; j < 4; j++) {
        int i = j * 256 + t;
        if (i < 960) o[i] = f2bf(v[j] * inv);
    }
}

// ---------------- head-mean + transpose: cm[b][n][c] = mean_h ctx[b*4+h][c][n] ----------------
__global__ __launch_bounds__(256) void mean_heads(const u16* __restrict__ ctx,
                                                  u16* __restrict__ cm, int C) {
    int b = blockIdx.z;
    int n0 = blockIdx.x * 64, c0 = blockIdx.y * 64;
    __shared__ float sm[64][65];
    int t = threadIdx.x;
    float acc[16];
#pragma unroll
    for (int j = 0; j < 16; j++) acc[j] = 0.f;
    for (int h = 0; h < 4; h++) {
        const u16* p = ctx + (size_t)(b * 4 + h) * C * 1024;
#pragma unroll
        for (int j = 0; j < 16; j++) {
            int lin = j * 256 + t;
            int cc = lin >> 6, nn = lin & 63;
            acc[j] += bf2f(p[(size_t)(c0 + cc) * 1024 + n0 + nn]);
        }
    }
#pragma unroll
    for (int j = 0; j < 16; j++) {
        int lin = j * 256 + t;
        sm[lin >> 6][lin & 63] = acc[j] * 0.25f;
    }
    __syncthreads();
#pragma unroll
    for (int j = 0; j < 16; j++) {
        int lin = j * 256 + t;
        int nn = lin >> 6, cc = lin & 63;
        cm[((size_t)b * 1024 + n0 + nn) * C + c0 + cc] = f2bf(sm[cc][nn]);
    }
}

extern "C" void kernel_launch(void* const* d_in, const int* in_sizes, int n_in,
                              void* d_out, int out_size, void* d_ws, size_t ws_size,
                              hipStream_t stream) {
    const int B = 8, NN = 1024, KV = 960;
    const int Cs[4] = {64, 128, 256, 512};
    const float* emb[4];
    for (int i = 0; i < 4; i++) emb[i] = (const float*)d_in[i];
    const float* embAll = (const float*)d_in[4];
    const float* Wq[4];
    for (int i = 0; i < 4; i++) Wq[i] = (const float*)d_in[5 + i];
    const float* Wk = (const float*)d_in[9];
    const float* Wv = (const float*)d_in[10];
    const float* Wo[4];
    for (int i = 0; i < 4; i++) Wo[i] = (const float*)d_in[11 + i];
    float* out = (float*)d_out;

    // ---- workspace layout (aliased; total ~234 MB) ----
    const size_t S1 = 62914560, S2 = 33554432, SKV = 62914560;
    const size_t SWQ = 2785280, SWO = 696320, SCM = 8388608;
    const size_t NEED = S1 + S2 + 2 * SKV + SWQ + SWO + SCM + 256;
    if (ws_size < NEED) return;

    char* base = (char*)d_ws;
    char* buf1 = base;
    char* buf2 = buf1 + S1;
    u16* Kt = (u16*)(buf2 + S2);        // [z][j=960][n=1024]
    u16* Vb = (u16*)((char*)Kt + SKV);  // [z][n=1024][j=960]
    char* pw = (char*)Vb + SKV;
    u16* wq[4];
    for (int i = 0; i < 4; i++) {
        wq[i] = (u16*)pw;
        pw += (size_t)4 * Cs[i] * Cs[i] * 2;
    }
    u16* wo[4];
    for (int i = 0; i < 4; i++) {
        wo[i] = (u16*)pw;
        pw += (size_t)Cs[i] * Cs[i] * 2;
    }
    u16* cmX = (u16*)pw;  // eI_i (branch input cast) then cm (head-mean out)
    pw += SCM;
    float* stats = (float*)pw;

    u16* eA = (u16*)buf1;
    u16* wk = (u16*)(buf1 + 15728640);
    u16* wv = (u16*)(buf1 + 23101440);
    float* sc = (float*)buf1;
    u16* ctx = (u16*)buf1;
    u16* Qt = (u16*)buf2;
    u16* pr = (u16*)buf2;

    auto castL = [&](const float* s, u16* d, size_t n) {
        int n4 = (int)(n / 4);
        int grid = (n4 + 255) / 256;
        cast_bf16<<<grid, 256, 0, stream>>>((const float4*)s, (u16x4*)d, n4);
    };
    castL(embAll, eA, (size_t)B * NN * KV);
    castL(Wk, wk, (size_t)4 * KV * KV);
    castL(Wv, wv, (size_t)4 * KV * KV);
    for (int i = 0; i < 4; i++) castL(Wq[i], wq[i], (size_t)4 * Cs[i] * Cs[i]);
    for (int i = 0; i < 4; i++) castL(Wo[i], wo[i], (size_t)Cs[i] * Cs[i]);

    float invs = 1.0f / sqrtf((float)KV);
    auto g = [](int n) { return (n + 127) / 128; };

    // Kt[z][j][n] = sum_k Wk[h][j][k] * embAll[b][n][k]
    gemm_nt128<u16><<<dim3(g(NN), g(KV), 32), 256, 0, stream>>>(
        wk, 0, (long)KV * KV, KV, eA, (long)NN * KV, 0, KV, Kt, (long)KV * NN, NN,
        KV, NN, KV, 4, 1.0f);
    // Vb[z][n][j] = sum_k embAll[b][n][k] * Wv[h][j][k]
    gemm_nt128<u16><<<dim3(g(KV), g(NN), 32), 256, 0, stream>>>(
        eA, (long)NN * KV, 0, KV, wv, 0, (long)KV * KV, KV, Vb, (long)NN * KV, KV,
        NN, KV, KV, 4, 1.0f);

    size_t off = 0;
    for (int i = 0; i < 4; i++) {
        int C = Cs[i];
        castL(emb[i], cmX, (size_t)B * NN * C);
        // Qt[z][c][n] = sum_d Wq[h][c][d] * emb_i[b][n][d]
        gemm_nt128<u16><<<dim3(g(NN), g(C), 32), 256, 0, stream>>>(
            wq[i], 0, (long)C * C, C, cmX, (long)NN * C, 0, C, Qt, (long)C * NN,
            NN, C, NN, C, 4, 1.0f);
        // sc[z][c][k] = invs * sum_n Qt[z][c][n] * Kt[z][k][n]
        gemm_nt128<float><<<dim3(g(KV), g(C), 32), 256, 0, stream>>>(
            Qt, 4L * C * NN, (long)C * NN, NN, Kt, 4L * KV * NN, (long)KV * NN, NN,
            sc, (long)C * KV, KV, C, KV, NN, 4, invs);
        // instance-norm stats over each [C,960] plane
        in_stats<<<32, 256, 0, stream>>>(sc, stats, C * KV);
        // normalize + softmax rows -> bf16 probs
        norm_softmax<<<32 * C, 256, 0, stream>>>(sc, stats, pr, C);
        // ctx[z][c][n] = sum_k pr[z][c][k] * Vb[z][n][k]
        gemm_nt128<u16><<<dim3(g(NN), g(C), 32), 256, 0, stream>>>(
            pr, 4L * C * KV, (long)C * KV, KV, Vb, 4L * NN * KV, (long)NN * KV, KV,
            ctx, (long)C * NN, NN, C, NN, KV, 4, 1.0f);
        // head-mean + transpose -> cm[b][n][c] bf16
        mean_heads<<<dim3(NN / 64, C / 64, B), 256, 0, stream>>>(ctx, cmX, C);
        // out[b][n][c] = sum_d cm[b][n][d] * Wo[c][d]
        gemm_nt128<float><<<dim3(g(C), g(NN), B), 256, 0, stream>>>(
            cmX, (long)NN * C, 0, C, wo[i], 0, 0, C, out + off, (long)NN * C, C,
            NN, C, C, 1, 1.0f);
        off += (size_t)B * NN * C;
    }
}

// Round 4
// 801.891 us; speedup vs baseline: 1.4158x; 1.2852x over previous
//
#include <hip/hip_runtime.h>
#include <stdint.h>

typedef unsigned short u16;
typedef short bf16x8 __attribute__((ext_vector_type(8)));
typedef float f32x4 __attribute__((ext_vector_type(4)));
typedef u16 u16x4 __attribute__((ext_vector_type(4)));

__device__ __forceinline__ u16 f2bf(float f) {
    unsigned u = __builtin_bit_cast(unsigned, f);
    unsigned r = (u + 0x7fffu + ((u >> 16) & 1u)) >> 16;
    return (u16)r;
}
__device__ __forceinline__ float bf2f(u16 h) {
    unsigned u = ((unsigned)h) << 16;
    return __builtin_bit_cast(float, u);
}

typedef const __attribute__((address_space(1))) unsigned int* gptr_t;
typedef __attribute__((address_space(3))) unsigned int* lptr_t;
__device__ __forceinline__ void gload16(const void* g, void* l) {
    __builtin_amdgcn_global_load_lds((gptr_t)(uintptr_t)g, (lptr_t)(uintptr_t)l, 16, 0, 0);
}

// ---------------- cast f32 -> bf16 (vectorized) ----------------
__global__ __launch_bounds__(256) void cast_bf16(const float4* __restrict__ in,
                                                 u16x4* __restrict__ out, int n4) {
    int i = blockIdx.x * 256 + threadIdx.x;
    if (i < n4) {
        float4 f = in[i];
        u16x4 o = {f2bf(f.x), f2bf(f.y), f2bf(f.z), f2bf(f.w)};
        out[i] = o;
    }
}

// ---------------- NT GEMM (m97 structure): C[m,n] = alpha * sum_k A[m,k]*B[n,k] ----------------
// BM=BN=128, BK=64, 256 threads (4 waves in 2x2), wave computes 64x64 via 4x4 MFMA frags.
template <typename OUT>
__global__ __launch_bounds__(256) void gemm_nt128(
    const u16* __restrict__ A, long sAb, long sAh, int lda,
    const u16* __restrict__ B, long sBb, long sBh, int ldb,
    OUT* __restrict__ C, long sCz, int ldc,
    int M, int N, int K, int hdiv, float alpha) {
    __shared__ u16 sA[128 * 64];
    __shared__ u16 sB[128 * 64];
    int z = blockIdx.z, bb = z / hdiv, hh = z - bb * hdiv;
    const u16* Ab = A + (size_t)bb * sAb + (size_t)hh * sAh;
    const u16* Bb = B + (size_t)bb * sBb + (size_t)hh * sBh;
    OUT* Cb = C + (size_t)z * sCz;
    int tm = blockIdx.y * 128, tn = blockIdx.x * 128;
    int t = threadIdx.x, lane = t & 63, w = t >> 6;
    int wr = w >> 1, wc = w & 1;
    int r0 = t >> 3, c0 = (t & 7) * 8;
    f32x4 acc[4][4] = {};
    int la = lane & 15, lk = (lane >> 4) * 8;
    for (int k0 = 0; k0 < K; k0 += 64) {
#pragma unroll
        for (int i = 0; i < 4; i++) {
            int ar = tm + i * 32 + r0;
            if (ar > M - 1) ar = M - 1;
            gload16(Ab + (size_t)ar * lda + k0 + c0, &sA[(i * 256 + t) * 8]);
        }
#pragma unroll
        for (int i = 0; i < 4; i++) {
            int br = tn + i * 32 + r0;
            if (br > N - 1) br = N - 1;
            gload16(Bb + (size_t)br * ldb + k0 + c0, &sB[(i * 256 + t) * 8]);
        }
        __syncthreads();
#pragma unroll
        for (int kk = 0; kk < 64; kk += 32) {
            bf16x8 a[4], b[4];
#pragma unroll
            for (int mi = 0; mi < 4; mi++)
                a[mi] = *(const bf16x8*)&sA[(wr * 64 + mi * 16 + la) * 64 + kk + lk];
#pragma unroll
            for (int ni = 0; ni < 4; ni++)
                b[ni] = *(const bf16x8*)&sB[(wc * 64 + ni * 16 + la) * 64 + kk + lk];
#pragma unroll
            for (int mi = 0; mi < 4; mi++)
#pragma unroll
                for (int ni = 0; ni < 4; ni++)
                    acc[mi][ni] = __builtin_amdgcn_mfma_f32_16x16x32_bf16(
                        a[mi], b[ni], acc[mi][ni], 0, 0, 0);
        }
        __syncthreads();
    }
#pragma unroll
    for (int mi = 0; mi < 4; mi++)
#pragma unroll
        for (int ni = 0; ni < 4; ni++)
#pragma unroll
            for (int r = 0; r < 4; r++) {
                int m = tm + wr * 64 + mi * 16 + (lane >> 4) * 4 + r;
                int n = tn + wc * 64 + ni * 16 + la;
                if (m < M && n < N) {
                    float v = acc[mi][ni][r] * alpha;
                    if constexpr (sizeof(OUT) == 4)
                        Cb[(size_t)m * ldc + n] = v;
                    else
                        Cb[(size_t)m * ldc + n] = f2bf(v);
                }
            }
}

// ---------------- instance-norm stats, stage 1: per-(z,chunk) partial sums ----------------
// grid = (G, 32); deterministic: fixed loop order + fixed shuffle tree, fixed slot write.
__global__ __launch_bounds__(256) void in_stats1(const float* __restrict__ sc,
                                                 double* __restrict__ part,
                                                 int n4, int G) {
    int z = blockIdx.y, g = blockIdx.x, t = threadIdx.x;
    const float4* p = (const float4*)(sc + (size_t)z * n4 * 4);
    double s = 0.0, q = 0.0;
    for (int i = g * 256 + t; i < n4; i += G * 256) {
        float4 f = p[i];
        s += (double)f.x + f.y + f.z + f.w;
        q += (double)f.x * f.x + (double)f.y * f.y + (double)f.z * f.z + (double)f.w * f.w;
    }
#pragma unroll
    for (int o = 32; o; o >>= 1) {
        s += __shfl_down(s, o);
        q += __shfl_down(q, o);
    }
    __shared__ double rs[4], rq[4];
    int w = t >> 6;
    if ((t & 63) == 0) {
        rs[w] = s;
        rq[w] = q;
    }
    __syncthreads();
    if (t == 0) {
        double S = rs[0] + rs[1] + rs[2] + rs[3];
        double Q = rq[0] + rq[1] + rq[2] + rq[3];
        part[2 * ((size_t)z * G + g)] = S;
        part[2 * ((size_t)z * G + g) + 1] = Q;
    }
}

// ---------------- stage 2: reduce G partials per z -> mu, rsqrt(var+eps) ----------------
__global__ __launch_bounds__(64) void in_stats2(const double* __restrict__ part,
                                                float* __restrict__ stats, int cnt, int G) {
    int z = blockIdx.x, t = threadIdx.x;
    double s = 0.0, q = 0.0;
    if (t < G) {
        s = part[2 * ((size_t)z * G + t)];
        q = part[2 * ((size_t)z * G + t) + 1];
    }
#pragma unroll
    for (int o = 32; o; o >>= 1) {
        s += __shfl_down(s, o);
        q += __shfl_down(q, o);
    }
    if (t == 0) {
        float mu = (float)(s / cnt);
        float var = (float)(q / cnt) - mu * mu;
        stats[2 * z] = mu;
        stats[2 * z + 1] = rsqrtf(var + 1e-5f);
    }
}

// ---------------- normalize + row softmax (row length 960), write bf16 ----------------
__global__ __launch_bounds__(256) void norm_softmax(const float* __restrict__ sc,
                                                    const float* __restrict__ stats,
                                                    u16* __restrict__ pr, int C) {
    int row = blockIdx.x;
    int z = row / C;
    const float* x = sc + (size_t)row * 960;
    u16* o = pr + (size_t)row * 960;
    float mu = stats[2 * z], rs = stats[2 * z + 1];
    int t = threadIdx.x;
    float v[4];
    float mx = -1e30f;
#pragma unroll
    for (int j = 0; j < 4; j++) {
        int i = j * 256 + t;
        if (i < 960) {
            float y = (x[i] - mu) * rs;
            v[j] = y;
            mx = fmaxf(mx, y);
        } else
            v[j] = -1e30f;
    }
    __shared__ float r1[4], r2[4];
#pragma unroll
    for (int o_ = 32; o_; o_ >>= 1) mx = fmaxf(mx, __shfl_xor(mx, o_));
    int w = t >> 6;
    if ((t & 63) == 0) r1[w] = mx;
    __syncthreads();
    mx = fmaxf(fmaxf(r1[0], r1[1]), fmaxf(r1[2], r1[3]));
    float s = 0.f;
#pragma unroll
    for (int j = 0; j < 4; j++) {
        int i = j * 256 + t;
        if (i < 960) {
            v[j] = __expf(v[j] - mx);
            s += v[j];
        }
    }
#pragma unroll
    for (int o_ = 32; o_; o_ >>= 1) s += __shfl_xor(s, o_);
    if ((t & 63) == 0) r2[w] = s;
    __syncthreads();
    s = r2[0] + r2[1] + r2[2] + r2[3];
    float inv = 1.0f / s;
#pragma unroll
    for (int j = 0; j < 4; j++) {
        int i = j * 256 + t;
        if (i < 960) o[i] = f2bf(v[j] * inv);
    }
}

// ---------------- head-mean + transpose: cm[b][n][c] = mean_h ctx[b*4+h][c][n] ----------------
__global__ __launch_bounds__(256) void mean_heads(const u16* __restrict__ ctx,
                                                  u16* __restrict__ cm, int C) {
    int b = blockIdx.z;
    int n0 = blockIdx.x * 64, c0 = blockIdx.y * 64;
    __shared__ float sm[64][65];
    int t = threadIdx.x;
    float acc[16];
#pragma unroll
    for (int j = 0; j < 16; j++) acc[j] = 0.f;
    for (int h = 0; h < 4; h++) {
        const u16* p = ctx + (size_t)(b * 4 + h) * C * 1024;
#pragma unroll
        for (int j = 0; j < 16; j++) {
            int lin = j * 256 + t;
            int cc = lin >> 6, nn = lin & 63;
            acc[j] += bf2f(p[(size_t)(c0 + cc) * 1024 + n0 + nn]);
        }
    }
#pragma unroll
    for (int j = 0; j < 16; j++) {
        int lin = j * 256 + t;
        sm[lin >> 6][lin & 63] = acc[j] * 0.25f;
    }
    __syncthreads();
#pragma unroll
    for (int j = 0; j < 16; j++) {
        int lin = j * 256 + t;
        int nn = lin >> 6, cc = lin & 63;
        cm[((size_t)b * 1024 + n0 + nn) * C + c0 + cc] = f2bf(sm[cc][nn]);
    }
}

extern "C" void kernel_launch(void* const* d_in, const int* in_sizes, int n_in,
                              void* d_out, int out_size, void* d_ws, size_t ws_size,
                              hipStream_t stream) {
    const int B = 8, NN = 1024, KV = 960;
    const int Cs[4] = {64, 128, 256, 512};
    const float* emb[4];
    for (int i = 0; i < 4; i++) emb[i] = (const float*)d_in[i];
    const float* embAll = (const float*)d_in[4];
    const float* Wq[4];
    for (int i = 0; i < 4; i++) Wq[i] = (const float*)d_in[5 + i];
    const float* Wk = (const float*)d_in[9];
    const float* Wv = (const float*)d_in[10];
    const float* Wo[4];
    for (int i = 0; i < 4; i++) Wo[i] = (const float*)d_in[11 + i];
    float* out = (float*)d_out;

    // ---- workspace layout (aliased; total ~234 MB) ----
    const size_t S1 = 62914560, S2 = 33554432, SKV = 62914560;
    const size_t SWQ = 2785280, SWO = 696320, SCM = 8388608;
    const int G = 64;
    const size_t SPART = (size_t)32 * G * 2 * sizeof(double);  // 32 KB
    const size_t NEED = S1 + S2 + 2 * SKV + SWQ + SWO + SCM + SPART + 512;
    if (ws_size < NEED) return;

    char* base = (char*)d_ws;
    char* buf1 = base;
    char* buf2 = buf1 + S1;
    u16* Kt = (u16*)(buf2 + S2);        // [z][j=960][n=1024]
    u16* Vb = (u16*)((char*)Kt + SKV);  // [z][n=1024][j=960]
    char* pw = (char*)Vb + SKV;
    u16* wq[4];
    for (int i = 0; i < 4; i++) {
        wq[i] = (u16*)pw;
        pw += (size_t)4 * Cs[i] * Cs[i] * 2;
    }
    u16* wo[4];
    for (int i = 0; i < 4; i++) {
        wo[i] = (u16*)pw;
        pw += (size_t)Cs[i] * Cs[i] * 2;
    }
    u16* cmX = (u16*)pw;  // eI_i (branch input cast) then cm (head-mean out)
    pw += SCM;
    double* part = (double*)pw;
    pw += SPART;
    float* stats = (float*)pw;

    u16* eA = (u16*)buf1;
    u16* wk = (u16*)(buf1 + 15728640);
    u16* wv = (u16*)(buf1 + 23101440);
    float* sc = (float*)buf1;
    u16* ctx = (u16*)buf1;
    u16* Qt = (u16*)buf2;
    u16* pr = (u16*)buf2;

    auto castL = [&](const float* s, u16* d, size_t n) {
        int n4 = (int)(n / 4);
        int grid = (n4 + 255) / 256;
        cast_bf16<<<grid, 256, 0, stream>>>((const float4*)s, (u16x4*)d, n4);
    };
    castL(embAll, eA, (size_t)B * NN * KV);
    castL(Wk, wk, (size_t)4 * KV * KV);
    castL(Wv, wv, (size_t)4 * KV * KV);
    for (int i = 0; i < 4; i++) castL(Wq[i], wq[i], (size_t)4 * Cs[i] * Cs[i]);
    for (int i = 0; i < 4; i++) castL(Wo[i], wo[i], (size_t)Cs[i] * Cs[i]);

    float invs = 1.0f / sqrtf((float)KV);
    auto g = [](int n) { return (n + 127) / 128; };

    // Kt[z][j][n] = sum_k Wk[h][j][k] * embAll[b][n][k]
    gemm_nt128<u16><<<dim3(g(NN), g(KV), 32), 256, 0, stream>>>(
        wk, 0, (long)KV * KV, KV, eA, (long)NN * KV, 0, KV, Kt, (long)KV * NN, NN,
        KV, NN, KV, 4, 1.0f);
    // Vb[z][n][j] = sum_k embAll[b][n][k] * Wv[h][j][k]
    gemm_nt128<u16><<<dim3(g(KV), g(NN), 32), 256, 0, stream>>>(
        eA, (long)NN * KV, 0, KV, wv, 0, (long)KV * KV, KV, Vb, (long)NN * KV, KV,
        NN, KV, KV, 4, 1.0f);

    size_t off = 0;
    for (int i = 0; i < 4; i++) {
        int C = Cs[i];
        castL(emb[i], cmX, (size_t)B * NN * C);
        // Qt[z][c][n] = sum_d Wq[h][c][d] * emb_i[b][n][d]
        gemm_nt128<u16><<<dim3(g(NN), g(C), 32), 256, 0, stream>>>(
            wq[i], 0, (long)C * C, C, cmX, (long)NN * C, 0, C, Qt, (long)C * NN,
            NN, C, NN, C, 4, 1.0f);
        // sc[z][c][k] = invs * sum_n Qt[z][c][n] * Kt[z][k][n]
        gemm_nt128<float><<<dim3(g(KV), g(C), 32), 256, 0, stream>>>(
            Qt, 4L * C * NN, (long)C * NN, NN, Kt, 4L * KV * NN, (long)KV * NN, NN,
            sc, (long)C * KV, KV, C, KV, NN, 4, invs);
        // instance-norm stats over each [C,960] plane (two-stage, deterministic)
        in_stats1<<<dim3(G, 32), 256, 0, stream>>>(sc, part, C * 240, G);
        in_stats2<<<32, 64, 0, stream>>>(part, stats, C * KV, G);
        // normalize + softmax rows -> bf16 probs
        norm_softmax<<<32 * C, 256, 0, stream>>>(sc, stats, pr, C);
        // ctx[z][c][n] = sum_k pr[z][c][k] * Vb[z][n][k]
        gemm_nt128<u16><<<dim3(g(NN), g(C), 32), 256, 0, stream>>>(
            pr, 4L * C * KV, (long)C * KV, KV, Vb, 4L * NN * KV, (long)NN * KV, KV,
            ctx, (long)C * NN, NN, C, NN, KV, 4, 1.0f);
        // head-mean + transpose -> cm[b][n][c] bf16
        mean_heads<<<dim3(NN / 64, C / 64, B), 256, 0, stream>>>(ctx, cmX, C);
        // out[b][n][c] = sum_d cm[b][n][d] * Wo[c][d]
        gemm_nt128<float><<<dim3(g(C), g(NN), B), 256, 0, stream>>>(
            cmX, (long)NN * C, 0, C, wo[i], 0, 0, C, out + off, (long)NN * C, C,
            NN, C, C, 1, 1.0f);
        off += (size_t)B * NN * C;
    }
}

// Round 5
// 697.131 us; speedup vs baseline: 1.6286x; 1.1503x over previous
//
#include <hip/hip_runtime.h>
#include <stdint.h>

typedef unsigned short u16;
typedef short bf16x8 __attribute__((ext_vector_type(8)));
typedef float f32x4 __attribute__((ext_vector_type(4)));
typedef u16 u16x4 __attribute__((ext_vector_type(4)));

__device__ __forceinline__ u16 f2bf(float f) {
    unsigned u = __builtin_bit_cast(unsigned, f);
    unsigned r = (u + 0x7fffu + ((u >> 16) & 1u)) >> 16;
    return (u16)r;
}
__device__ __forceinline__ float bf2f(u16 h) {
    unsigned u = ((unsigned)h) << 16;
    return __builtin_bit_cast(float, u);
}

typedef const __attribute__((address_space(1))) unsigned int* gptr_t;
typedef __attribute__((address_space(3))) unsigned int* lptr_t;
__device__ __forceinline__ void gload16(const void* g, void* l) {
    __builtin_amdgcn_global_load_lds((gptr_t)(uintptr_t)g, (lptr_t)(uintptr_t)l, 16, 0, 0);
}

// branch tables: rows of the concatenated 960-row score/Q space
__device__ __constant__ int d_offs[4] = {0, 512, 768, 896};
__device__ __constant__ int d_cs[4] = {512, 256, 128, 64};

// ---------------- cast f32 -> bf16 (vectorized) ----------------
__global__ __launch_bounds__(256) void cast_bf16(const float4* __restrict__ in,
                                                 u16x4* __restrict__ out, int n4) {
    int i = blockIdx.x * 256 + threadIdx.x;
    if (i < n4) {
        float4 f = in[i];
        u16x4 o = {f2bf(f.x), f2bf(f.y), f2bf(f.z), f2bf(f.w)};
        out[i] = o;
    }
}

// ---------------- NT GEMM (m97 structure): C[m,n] = alpha * sum_k A[m,k]*B[n,k] ----------------
// BM=BN=128, BK=64, 256 threads (4 waves in 2x2), wave computes 64x64 via 4x4 MFMA frags.
template <typename OUT>
__global__ __launch_bounds__(256) void gemm_nt128(
    const u16* __restrict__ A, long sAb, long sAh, int lda,
    const u16* __restrict__ B, long sBb, long sBh, int ldb,
    OUT* __restrict__ C, long sCz, int ldc,
    int M, int N, int K, int hdiv, float alpha) {
    __shared__ u16 sA[128 * 64];
    __shared__ u16 sB[128 * 64];
    int z = blockIdx.z, bb = z / hdiv, hh = z - bb * hdiv;
    const u16* Ab = A + (size_t)bb * sAb + (size_t)hh * sAh;
    const u16* Bb = B + (size_t)bb * sBb + (size_t)hh * sBh;
    OUT* Cb = C + (size_t)z * sCz;
    int tm = blockIdx.y * 128, tn = blockIdx.x * 128;
    int t = threadIdx.x, lane = t & 63, w = t >> 6;
    int wr = w >> 1, wc = w & 1;
    int r0 = t >> 3, c0 = (t & 7) * 8;
    f32x4 acc[4][4] = {};
    int la = lane & 15, lk = (lane >> 4) * 8;
    for (int k0 = 0; k0 < K; k0 += 64) {
#pragma unroll
        for (int i = 0; i < 4; i++) {
            int ar = tm + i * 32 + r0;
            if (ar > M - 1) ar = M - 1;
            gload16(Ab + (size_t)ar * lda + k0 + c0, &sA[(i * 256 + t) * 8]);
        }
#pragma unroll
        for (int i = 0; i < 4; i++) {
            int br = tn + i * 32 + r0;
            if (br > N - 1) br = N - 1;
            gload16(Bb + (size_t)br * ldb + k0 + c0, &sB[(i * 256 + t) * 8]);
        }
        __syncthreads();
#pragma unroll
        for (int kk = 0; kk < 64; kk += 32) {
            bf16x8 a[4], b[4];
#pragma unroll
            for (int mi = 0; mi < 4; mi++)
                a[mi] = *(const bf16x8*)&sA[(wr * 64 + mi * 16 + la) * 64 + kk + lk];
#pragma unroll
            for (int ni = 0; ni < 4; ni++)
                b[ni] = *(const bf16x8*)&sB[(wc * 64 + ni * 16 + la) * 64 + kk + lk];
#pragma unroll
            for (int mi = 0; mi < 4; mi++)
#pragma unroll
                for (int ni = 0; ni < 4; ni++)
                    acc[mi][ni] = __builtin_amdgcn_mfma_f32_16x16x32_bf16(
                        a[mi], b[ni], acc[mi][ni], 0, 0, 0);
        }
        __syncthreads();
    }
#pragma unroll
    for (int mi = 0; mi < 4; mi++)
#pragma unroll
        for (int ni = 0; ni < 4; ni++)
#pragma unroll
            for (int r = 0; r < 4; r++) {
                int m = tm + wr * 64 + mi * 16 + (lane >> 4) * 4 + r;
                int n = tn + wc * 64 + ni * 16 + la;
                if (m < M && n < N) {
                    float v = acc[mi][ni][r] * alpha;
                    if constexpr (sizeof(OUT) == 4)
                        Cb[(size_t)m * ldc + n] = v;
                    else
                        Cb[(size_t)m * ldc + n] = f2bf(v);
                }
            }
}

// ---------------- instance-norm stats, stage 1 (bf16 input, two-stage deterministic) ----------------
// mode 1: grid (G, 128) planes over concatenated [z][960][960]: p -> z=p>>2, branch i=p&3
// mode 0: grid (G, 32) planes of [z][C][960]
__global__ __launch_bounds__(256) void in_stats1(const u16* __restrict__ sc,
                                                 double* __restrict__ part,
                                                 int G, int mode, int C) {
    int p = blockIdx.y, g = blockIdx.x, t = threadIdx.x;
    size_t base;
    int n8;
    if (mode) {
        int z = p >> 2, i = p & 3;
        base = (size_t)z * 921600 + (size_t)d_offs[i] * 960;
        n8 = d_cs[i] * 120;
    } else {
        base = (size_t)p * C * 960;
        n8 = C * 120;
    }
    const u16* x = sc + base;
    double s = 0.0, q = 0.0;
    for (int i = g * 256 + t; i < n8; i += G * 256) {
        u16x4 a = *(const u16x4*)&x[i * 8];
        u16x4 b = *(const u16x4*)&x[i * 8 + 4];
#pragma unroll
        for (int j = 0; j < 4; j++) {
            float fa = bf2f(a[j]), fb = bf2f(b[j]);
            s += (double)fa + (double)fb;
            q += (double)fa * fa + (double)fb * fb;
        }
    }
#pragma unroll
    for (int o = 32; o; o >>= 1) {
        s += __shfl_down(s, o);
        q += __shfl_down(q, o);
    }
    __shared__ double rs[4], rq[4];
    int w = t >> 6;
    if ((t & 63) == 0) {
        rs[w] = s;
        rq[w] = q;
    }
    __syncthreads();
    if (t == 0) {
        part[2 * ((size_t)p * G + g)] = rs[0] + rs[1] + rs[2] + rs[3];
        part[2 * ((size_t)p * G + g) + 1] = rq[0] + rq[1] + rq[2] + rq[3];
    }
}

// ---------------- stage 2: reduce G partials per plane -> mu, rsqrt(var+eps) ----------------
__global__ __launch_bounds__(64) void in_stats2(const double* __restrict__ part,
                                                float* __restrict__ stats,
                                                int G, int mode, int C) {
    int p = blockIdx.x, t = threadIdx.x;
    int cnt = (mode ? d_cs[p & 3] : C) * 960;
    double s = 0.0, q = 0.0;
    if (t < G) {
        s = part[2 * ((size_t)p * G + t)];
        q = part[2 * ((size_t)p * G + t) + 1];
    }
#pragma unroll
    for (int o = 32; o; o >>= 1) {
        s += __shfl_down(s, o);
        q += __shfl_down(q, o);
    }
    if (t == 0) {
        float mu = (float)(s / cnt);
        float var = (float)(q / cnt) - mu * mu;
        stats[2 * p] = mu;
        stats[2 * p + 1] = rsqrtf(var + 1e-5f);
    }
}

// ---------------- normalize + row softmax, IN-PLACE on bf16 rows of length 960 ----------------
// mode 1: row in [0, 32*960), plane = z*4 + branch(r). mode 0: plane = row / C.
__global__ __launch_bounds__(256) void norm_softmax_ip(u16* sc,
                                                       const float* __restrict__ stats,
                                                       int mode, int C) {
    int row = blockIdx.x;
    int plane;
    if (mode) {
        int z = row / 960, r = row - z * 960;
        int i = r < 512 ? 0 : (r < 768 ? 1 : (r < 896 ? 2 : 3));
        plane = z * 4 + i;
    } else
        plane = row / C;
    u16* x = sc + (size_t)row * 960;
    float mu = stats[2 * plane], rs = stats[2 * plane + 1];
    int t = threadIdx.x;
    bool act = t < 240;
    float v[4];
    float mx = -1e30f;
    if (act) {
        u16x4 d = *(const u16x4*)&x[t * 4];
#pragma unroll
        for (int j = 0; j < 4; j++) {
            v[j] = (bf2f(d[j]) - mu) * rs;
            mx = fmaxf(mx, v[j]);
        }
    }
    __shared__ float r1[4], r2[4];
#pragma unroll
    for (int o = 32; o; o >>= 1) mx = fmaxf(mx, __shfl_xor(mx, o));
    int w = t >> 6;
    if ((t & 63) == 0) r1[w] = mx;
    __syncthreads();
    mx = fmaxf(fmaxf(r1[0], r1[1]), fmaxf(r1[2], r1[3]));
    float s = 0.f;
    if (act) {
#pragma unroll
        for (int j = 0; j < 4; j++) {
            v[j] = __expf(v[j] - mx);
            s += v[j];
        }
    }
#pragma unroll
    for (int o = 32; o; o >>= 1) s += __shfl_xor(s, o);
    if ((t & 63) == 0) r2[w] = s;
    __syncthreads();
    s = r2[0] + r2[1] + r2[2] + r2[3];
    float inv = 1.0f / s;
    if (act) {
        u16x4 o;
#pragma unroll
        for (int j = 0; j < 4; j++) o[j] = f2bf(v[j] * inv);
        *(u16x4*)&x[t * 4] = o;
    }
}

// ---------------- head-mean + transpose: cm[b][n][c] = mean_h ctx[(b*4+h)*ps + c*1024 + n] ----------------
__global__ __launch_bounds__(256) void mean_heads(const u16* __restrict__ ctx, long ps,
                                                  u16* __restrict__ cm, int C) {
    int b = blockIdx.z;
    int n0 = blockIdx.x * 64, c0 = blockIdx.y * 64;
    __shared__ float sm[64][65];
    int t = threadIdx.x;
    float acc[16];
#pragma unroll
    for (int j = 0; j < 16; j++) acc[j] = 0.f;
    for (int h = 0; h < 4; h++) {
        const u16* p = ctx + (size_t)(b * 4 + h) * ps;
#pragma unroll
        for (int j = 0; j < 16; j++) {
            int lin = j * 256 + t;
            int cc = lin >> 6, nn = lin & 63;
            acc[j] += bf2f(p[(size_t)(c0 + cc) * 1024 + n0 + nn]);
        }
    }
#pragma unroll
    for (int j = 0; j < 16; j++) {
        int lin = j * 256 + t;
        sm[lin >> 6][lin & 63] = acc[j] * 0.25f;
    }
    __syncthreads();
#pragma unroll
    for (int j = 0; j < 16; j++) {
        int lin = j * 256 + t;
        int nn = lin >> 6, cc = lin & 63;
        cm[((size_t)b * 1024 + n0 + nn) * C + c0 + cc] = f2bf(sm[cc][nn]);
    }
}

extern "C" void kernel_launch(void* const* d_in, const int* in_sizes, int n_in,
                              void* d_out, int out_size, void* d_ws, size_t ws_size,
                              hipStream_t stream) {
    const int B = 8, NN = 1024, KV = 960;
    const int Cs[4] = {64, 128, 256, 512};          // input order
    const int ord[4] = {3, 2, 1, 0};                // process 512,256,128,64 for row-concat
    const int offs[4] = {0, 512, 768, 896};          // row offset of ord[j] in the 960 space
    const float* emb[4];
    for (int i = 0; i < 4; i++) emb[i] = (const float*)d_in[i];
    const float* embAll = (const float*)d_in[4];
    const float* Wq[4];
    for (int i = 0; i < 4; i++) Wq[i] = (const float*)d_in[5 + i];
    const float* Wk = (const float*)d_in[9];
    const float* Wv = (const float*)d_in[10];
    const float* Wo[4];
    for (int i = 0; i < 4; i++) Wo[i] = (const float*)d_in[11 + i];
    float* out = (float*)d_out;
    size_t outOff[4];
    {
        size_t o = 0;
        for (int i = 0; i < 4; i++) { outOff[i] = o; o += (size_t)B * NN * Cs[i]; }
    }

    const size_t SKV = 62914560;   // Kt / Vb / Qt_all / ctx_all (bf16, 32*960*1024 or 32*1024*960)
    const size_t SSC = 58982400;   // scores bf16 32*960*960
    const size_t SWQ = 2785280, SWO = 696320, SCM = 8388608;
    const size_t SPART = 131072, SST = 1024;
    const size_t SMALL = SWQ + SWO + SCM + SPART + SST;

    // batched layout: bufA(sc) + bufB(Qt/ctx) + Kt + Vb + small
    const size_t NEED_BAT = SSC + 3 * SKV + SMALL + 512;

    float invs = 1.0f / sqrtf((float)KV);
    auto g128 = [](int n) { return (n + 127) / 128; };

    if (ws_size >= NEED_BAT) {
        // ================= batched path =================
        char* p = (char*)d_ws;
        u16* scB = (u16*)p;            p += SSC;   // init: eA/wk/wv; then scores(bf16)->probs in-place
        u16* QtB = (u16*)p;            p += SKV;   // Qt_all [z][960][1024] -> ctx_all [z][960][1024]
        u16* Kt = (u16*)p;             p += SKV;   // [z][960][1024]
        u16* Vb = (u16*)p;             p += SKV;   // [z][1024][960]
        u16* wq[4];
        for (int i = 0; i < 4; i++) { wq[i] = (u16*)p; p += (size_t)4 * Cs[i] * Cs[i] * 2; }
        u16* wo[4];
        for (int i = 0; i < 4; i++) { wo[i] = (u16*)p; p += (size_t)Cs[i] * Cs[i] * 2; }
        u16* cmX = (u16*)p;            p += SCM;
        double* part = (double*)p;     p += SPART;
        float* stats = (float*)p;

        u16* eA = scB;
        u16* wk = (u16*)((char*)scB + 15728640);
        u16* wv = (u16*)((char*)scB + 23101440);
        u16* ctxB = QtB;

        auto castL = [&](const float* s, u16* d, size_t n) {
            int n4 = (int)(n / 4);
            cast_bf16<<<(n4 + 255) / 256, 256, 0, stream>>>((const float4*)s, (u16x4*)d, n4);
        };
        castL(embAll, eA, (size_t)B * NN * KV);
        castL(Wk, wk, (size_t)4 * KV * KV);
        castL(Wv, wv, (size_t)4 * KV * KV);
        for (int i = 0; i < 4; i++) castL(Wq[i], wq[i], (size_t)4 * Cs[i] * Cs[i]);
        for (int i = 0; i < 4; i++) castL(Wo[i], wo[i], (size_t)Cs[i] * Cs[i]);

        // Kt[z][j][n] ; Vb[z][n][j]
        gemm_nt128<u16><<<dim3(8, 8, 32), 256, 0, stream>>>(
            wk, 0, (long)KV * KV, KV, eA, (long)NN * KV, 0, KV, Kt, 983040L, NN,
            KV, NN, KV, 4, 1.0f);
        gemm_nt128<u16><<<dim3(8, 8, 32), 256, 0, stream>>>(
            eA, (long)NN * KV, 0, KV, wv, 0, (long)KV * KV, KV, Vb, 983040L, KV,
            NN, KV, KV, 4, 1.0f);

        // Q-proj all branches into concatenated QtB rows
        for (int j = 0; j < 4; j++) {
            int i = ord[j], C = Cs[i];
            castL(emb[i], cmX, (size_t)B * NN * C);
            gemm_nt128<u16><<<dim3(8, g128(C), 32), 256, 0, stream>>>(
                wq[i], 0, (long)C * C, C, cmX, (long)NN * C, 0, C,
                QtB + (size_t)offs[j] * 1024, 983040L, NN, C, NN, C, 4, 1.0f);
        }
        // one big QK: sc[z][960][960] bf16
        gemm_nt128<u16><<<dim3(8, 8, 32), 256, 0, stream>>>(
            QtB, 983040L, 0, NN, Kt, 983040L, 0, NN, scB, 921600L, KV,
            960, KV, NN, 1, invs);
        // instance-norm stats (128 planes) + in-place softmax
        in_stats1<<<dim3(16, 128), 256, 0, stream>>>(scB, part, 16, 1, 0);
        in_stats2<<<128, 64, 0, stream>>>(part, stats, 16, 1, 0);
        norm_softmax_ip<<<32 * 960, 256, 0, stream>>>(scB, stats, 1, 0);
        // one big PV: ctx[z][960][1024]
        gemm_nt128<u16><<<dim3(8, 8, 32), 256, 0, stream>>>(
            scB, 921600L, 0, KV, Vb, 983040L, 0, KV, ctxB, 983040L, NN,
            960, NN, KV, 1, 1.0f);
        // per-branch: head-mean + out-proj
        for (int j = 0; j < 4; j++) {
            int i = ord[j], C = Cs[i];
            mean_heads<<<dim3(16, C / 64, B), 256, 0, stream>>>(
                ctxB + (size_t)offs[j] * 1024, 983040L, cmX, C);
            gemm_nt128<float><<<dim3(g128(C), 8, B), 256, 0, stream>>>(
                cmX, (long)NN * C, 0, C, wo[i], 0, 0, C, out + outOff[i],
                (long)NN * C, C, NN, C, C, 1, 1.0f);
        }
    } else {
        // ================= fallback per-branch path (~205 MB) =================
        const size_t S1 = 33554432, S2 = 33554432;
        if (ws_size < S1 + S2 + 2 * SKV + SMALL + 512) return;
        char* p = (char*)d_ws;
        char* buf1 = p;                p += S1;    // init eA/wk/wv -> sc(bf16)->probs in-place
        char* buf2 = p;                p += S2;    // Qt -> ctx
        u16* Kt = (u16*)p;             p += SKV;
        u16* Vb = (u16*)p;             p += SKV;
        u16* wq[4];
        for (int i = 0; i < 4; i++) { wq[i] = (u16*)p; p += (size_t)4 * Cs[i] * Cs[i] * 2; }
        u16* wo[4];
        for (int i = 0; i < 4; i++) { wo[i] = (u16*)p; p += (size_t)Cs[i] * Cs[i] * 2; }
        u16* cmX = (u16*)p;            p += SCM;
        double* part = (double*)p;     p += SPART;
        float* stats = (float*)p;

        u16* eA = (u16*)buf1;
        u16* wk = (u16*)(buf1 + 15728640);
        u16* wv = (u16*)(buf1 + 23101440);
        u16* sc = (u16*)buf1;
        u16* Qt = (u16*)buf2;
        u16* ctx = (u16*)buf2;

        auto castL = [&](const float* s, u16* d, size_t n) {
            int n4 = (int)(n / 4);
            cast_bf16<<<(n4 + 255) / 256, 256, 0, stream>>>((const float4*)s, (u16x4*)d, n4);
        };
        castL(embAll, eA, (size_t)B * NN * KV);
        castL(Wk, wk, (size_t)4 * KV * KV);
        castL(Wv, wv, (size_t)4 * KV * KV);
        for (int i = 0; i < 4; i++) castL(Wq[i], wq[i], (size_t)4 * Cs[i] * Cs[i]);
        for (int i = 0; i < 4; i++) castL(Wo[i], wo[i], (size_t)Cs[i] * Cs[i]);

        gemm_nt128<u16><<<dim3(8, 8, 32), 256, 0, stream>>>(
            wk, 0, (long)KV * KV, KV, eA, (long)NN * KV, 0, KV, Kt, 983040L, NN,
            KV, NN, KV, 4, 1.0f);
        gemm_nt128<u16><<<dim3(8, 8, 32), 256, 0, stream>>>(
            eA, (long)NN * KV, 0, KV, wv, 0, (long)KV * KV, KV, Vb, 983040L, KV,
            NN, KV, KV, 4, 1.0f);

        for (int i = 0; i < 4; i++) {
            int C = Cs[i];
            castL(emb[i], cmX, (size_t)B * NN * C);
            gemm_nt128<u16><<<dim3(8, g128(C), 32), 256, 0, stream>>>(
                wq[i], 0, (long)C * C, C, cmX, (long)NN * C, 0, C, Qt, (long)C * NN,
                NN, C, NN, C, 4, 1.0f);
            gemm_nt128<u16><<<dim3(8, g128(C), 32), 256, 0, stream>>>(
                Qt, (long)C * NN, 0, NN, Kt, 983040L, 0, NN, sc, (long)C * KV, KV,
                C, KV, NN, 1, invs);
            in_stats1<<<dim3(64, 32), 256, 0, stream>>>(sc, part, 64, 0, C);
            in_stats2<<<32, 64, 0, stream>>>(part, stats, 64, 0, C);
            norm_softmax_ip<<<32 * C, 256, 0, stream>>>(sc, stats, 0, C);
            gemm_nt128<u16><<<dim3(8, g128(C), 32), 256, 0, stream>>>(
                sc, (long)C * KV, 0, KV, Vb, 983040L, 0, KV, ctx, (long)C * NN, NN,
                C, NN, KV, 1, 1.0f);
            mean_heads<<<dim3(16, C / 64, B), 256, 0, stream>>>(
                ctx, (long)C * NN, cmX, C);
            gemm_nt128<float><<<dim3(g128(C), 8, B), 256, 0, stream>>>(
                cmX, (long)NN * C, 0, C, wo[i], 0, 0, C, out + outOff[i],
                (long)NN * C, C, NN, C, C, 1, 1.0f);
        }
    }
}

// Round 6
// 625.872 us; speedup vs baseline: 1.8140x; 1.1139x over previous
//
#include <hip/hip_runtime.h>
#include <stdint.h>

typedef unsigned short u16;
typedef short bf16x8 __attribute__((ext_vector_type(8)));
typedef float f32x4 __attribute__((ext_vector_type(4)));
typedef u16 u16x4 __attribute__((ext_vector_type(4)));

__device__ __forceinline__ u16 f2bf(float f) {
    unsigned u = __builtin_bit_cast(unsigned, f);
    unsigned r = (u + 0x7fffu + ((u >> 16) & 1u)) >> 16;
    return (u16)r;
}
__device__ __forceinline__ float bf2f(u16 h) {
    unsigned u = ((unsigned)h) << 16;
    return __builtin_bit_cast(float, u);
}

typedef const __attribute__((address_space(1))) unsigned int* gptr_t;
typedef __attribute__((address_space(3))) unsigned int* lptr_t;
__device__ __forceinline__ void gload16(const void* g, void* l) {
    __builtin_amdgcn_global_load_lds((gptr_t)(uintptr_t)g, (lptr_t)(uintptr_t)l, 16, 0, 0);
}

// branch tables: rows of the concatenated 960-row score/Q space
__device__ __constant__ int d_offs[4] = {0, 512, 768, 896};
__device__ __constant__ int d_cs[4] = {512, 256, 128, 64};

// ---------------- cast f32 -> bf16 (vectorized) ----------------
__global__ __launch_bounds__(256) void cast_bf16(const float4* __restrict__ in,
                                                 u16x4* __restrict__ out, int n4) {
    int i = blockIdx.x * 256 + threadIdx.x;
    if (i < n4) {
        float4 f = in[i];
        u16x4 o = {f2bf(f.x), f2bf(f.y), f2bf(f.z), f2bf(f.w)};
        out[i] = o;
    }
}

// ---------------- NT GEMM (m97 structure): C[m,n] = alpha * sum_k A[m,k]*B[n,k] ----------------
// BM=BN=128, BK=64, 256 threads (4 waves in 2x2), wave computes 64x64 via 4x4 MFMA frags.
// z -> (bb=z/hdiv, hh=z%hdiv); separate bb/hh strides for A, B, C.
// XCD-bijective block swizzle (m204); staging pointers hoisted out of K-loop.
template <typename OUT>
__global__ __launch_bounds__(256) void gemm_nt128(
    const u16* __restrict__ A, long sAb, long sAh, int lda,
    const u16* __restrict__ B, long sBb, long sBh, int ldb,
    OUT* __restrict__ C, long sCb, long sCh, int ldc,
    int M, int N, int K, int hdiv, float alpha) {
    __shared__ u16 sA[128 * 64];
    __shared__ u16 sB[128 * 64];
    // bijective XCD swizzle of the flat block id
    int gx = gridDim.x, gy = gridDim.y;
    int nwg = gx * gy * gridDim.z;
    int orig = blockIdx.x + gx * (blockIdx.y + gy * blockIdx.z);
    int q = nwg >> 3, r = nwg & 7;
    int xcd = orig & 7, seq = orig >> 3;
    int wg = (xcd < r ? xcd * (q + 1) : r * (q + 1) + (xcd - r) * q) + seq;
    int bx = wg % gx, tmpw = wg / gx;
    int by = tmpw % gy, bz = tmpw / gy;

    int bb = bz / hdiv, hh = bz - bb * hdiv;
    const u16* Ab = A + (size_t)bb * sAb + (size_t)hh * sAh;
    const u16* Bb = B + (size_t)bb * sBb + (size_t)hh * sBh;
    OUT* Cb = C + (size_t)bb * sCb + (size_t)hh * sCh;
    int tm = by * 128, tn = bx * 128;
    int t = threadIdx.x, lane = t & 63, w = t >> 6;
    int wr = w >> 1, wc = w & 1;
    int r0 = t >> 3, c0 = (t & 7) * 8;
    // hoisted, clamped staging pointers (k0-invariant)
    const u16* gA[4];
    const u16* gB[4];
#pragma unroll
    for (int i = 0; i < 4; i++) {
        int ar = tm + i * 32 + r0;
        if (ar > M - 1) ar = M - 1;
        gA[i] = Ab + (size_t)ar * lda + c0;
    }
#pragma unroll
    for (int i = 0; i < 4; i++) {
        int br = tn + i * 32 + r0;
        if (br > N - 1) br = N - 1;
        gB[i] = Bb + (size_t)br * ldb + c0;
    }
    f32x4 acc[4][4] = {};
    int la = lane & 15, lk = (lane >> 4) * 8;
    for (int k0 = 0; k0 < K; k0 += 64) {
#pragma unroll
        for (int i = 0; i < 4; i++) {
            gload16(gA[i], &sA[(i * 256 + t) * 8]);
            gA[i] += 64;
        }
#pragma unroll
        for (int i = 0; i < 4; i++) {
            gload16(gB[i], &sB[(i * 256 + t) * 8]);
            gB[i] += 64;
        }
        __syncthreads();
#pragma unroll
        for (int kk = 0; kk < 64; kk += 32) {
            bf16x8 a[4], b[4];
#pragma unroll
            for (int mi = 0; mi < 4; mi++)
                a[mi] = *(const bf16x8*)&sA[(wr * 64 + mi * 16 + la) * 64 + kk + lk];
#pragma unroll
            for (int ni = 0; ni < 4; ni++)
                b[ni] = *(const bf16x8*)&sB[(wc * 64 + ni * 16 + la) * 64 + kk + lk];
#pragma unroll
            for (int mi = 0; mi < 4; mi++)
#pragma unroll
                for (int ni = 0; ni < 4; ni++)
                    acc[mi][ni] = __builtin_amdgcn_mfma_f32_16x16x32_bf16(
                        a[mi], b[ni], acc[mi][ni], 0, 0, 0);
        }
        __syncthreads();
    }
#pragma unroll
    for (int mi = 0; mi < 4; mi++)
#pragma unroll
        for (int ni = 0; ni < 4; ni++)
#pragma unroll
            for (int r_ = 0; r_ < 4; r_++) {
                int m = tm + wr * 64 + mi * 16 + (lane >> 4) * 4 + r_;
                int n = tn + wc * 64 + ni * 16 + la;
                if (m < M && n < N) {
                    float v = acc[mi][ni][r_] * alpha;
                    if constexpr (sizeof(OUT) == 4)
                        Cb[(size_t)m * ldc + n] = v;
                    else
                        Cb[(size_t)m * ldc + n] = f2bf(v);
                }
            }
}

// ---------------- instance-norm stats, stage 1 (bf16 input, two-stage deterministic) ----------------
// mode 1: grid (G, 128) planes over concatenated [z][960][960]: p -> z=p>>2, branch i=p&3
// mode 0: grid (G, 32) planes of [z][C][960]
__global__ __launch_bounds__(256) void in_stats1(const u16* __restrict__ sc,
                                                 double* __restrict__ part,
                                                 int G, int mode, int C) {
    int p = blockIdx.y, g = blockIdx.x, t = threadIdx.x;
    size_t base;
    int n8;
    if (mode) {
        int z = p >> 2, i = p & 3;
        base = (size_t)z * 921600 + (size_t)d_offs[i] * 960;
        n8 = d_cs[i] * 120;
    } else {
        base = (size_t)p * C * 960;
        n8 = C * 120;
    }
    const u16* x = sc + base;
    double s = 0.0, q = 0.0;
    for (int i = g * 256 + t; i < n8; i += G * 256) {
        u16x4 a = *(const u16x4*)&x[i * 8];
        u16x4 b = *(const u16x4*)&x[i * 8 + 4];
#pragma unroll
        for (int j = 0; j < 4; j++) {
            float fa = bf2f(a[j]), fb = bf2f(b[j]);
            s += (double)fa + (double)fb;
            q += (double)fa * fa + (double)fb * fb;
        }
    }
#pragma unroll
    for (int o = 32; o; o >>= 1) {
        s += __shfl_down(s, o);
        q += __shfl_down(q, o);
    }
    __shared__ double rs[4], rq[4];
    int w = t >> 6;
    if ((t & 63) == 0) {
        rs[w] = s;
        rq[w] = q;
    }
    __syncthreads();
    if (t == 0) {
        part[2 * ((size_t)p * G + g)] = rs[0] + rs[1] + rs[2] + rs[3];
        part[2 * ((size_t)p * G + g) + 1] = rq[0] + rq[1] + rq[2] + rq[3];
    }
}

// ---------------- stage 2: reduce G partials per plane -> mu, rsqrt(var+eps) ----------------
__global__ __launch_bounds__(64) void in_stats2(const double* __restrict__ part,
                                                float* __restrict__ stats,
                                                int G, int mode, int C) {
    int p = blockIdx.x, t = threadIdx.x;
    int cnt = (mode ? d_cs[p & 3] : C) * 960;
    double s = 0.0, q = 0.0;
    if (t < G) {
        s = part[2 * ((size_t)p * G + t)];
        q = part[2 * ((size_t)p * G + t) + 1];
    }
#pragma unroll
    for (int o = 32; o; o >>= 1) {
        s += __shfl_down(s, o);
        q += __shfl_down(q, o);
    }
    if (t == 0) {
        float mu = (float)(s / cnt);
        float var = (float)(q / cnt) - mu * mu;
        stats[2 * p] = mu;
        stats[2 * p + 1] = rsqrtf(var + 1e-5f);
    }
}

// ---------------- normalize + softmax -> prCat[b][c][h*960+k] (batched path) ----------------
__global__ __launch_bounds__(256) void norm_softmax_cat(const u16* __restrict__ sc,
                                                        const float* __restrict__ stats,
                                                        u16* __restrict__ prB) {
    int row = blockIdx.x;  // [0, 32*960): z*960 + c
    int z = row / 960, c = row - z * 960;
    int i = c < 512 ? 0 : (c < 768 ? 1 : (c < 896 ? 2 : 3));
    int plane = z * 4 + i;
    int b = z >> 2, h = z & 3;
    const u16* x = sc + (size_t)row * 960;
    u16* o = prB + (((size_t)b * 960 + c) * 4 + h) * 960;
    float mu = stats[2 * plane], rs = stats[2 * plane + 1];
    int t = threadIdx.x;
    bool act = t < 240;
    float v[4];
    float mx = -1e30f;
    if (act) {
        u16x4 d = *(const u16x4*)&x[t * 4];
#pragma unroll
        for (int j = 0; j < 4; j++) {
            v[j] = (bf2f(d[j]) - mu) * rs;
            mx = fmaxf(mx, v[j]);
        }
    }
    __shared__ float r1[4], r2[4];
#pragma unroll
    for (int o_ = 32; o_; o_ >>= 1) mx = fmaxf(mx, __shfl_xor(mx, o_));
    int w = t >> 6;
    if ((t & 63) == 0) r1[w] = mx;
    __syncthreads();
    mx = fmaxf(fmaxf(r1[0], r1[1]), fmaxf(r1[2], r1[3]));
    float s = 0.f;
    if (act) {
#pragma unroll
        for (int j = 0; j < 4; j++) {
            v[j] = __expf(v[j] - mx);
            s += v[j];
        }
    }
#pragma unroll
    for (int o_ = 32; o_; o_ >>= 1) s += __shfl_xor(s, o_);
    if ((t & 63) == 0) r2[w] = s;
    __syncthreads();
    s = r2[0] + r2[1] + r2[2] + r2[3];
    float inv = 1.0f / s;
    if (act) {
        u16x4 ov;
#pragma unroll
        for (int j = 0; j < 4; j++) ov[j] = f2bf(v[j] * inv);
        *(u16x4*)&o[t * 4] = ov;
    }
}

// ---------------- normalize + softmax, in-place (fallback path) ----------------
__global__ __launch_bounds__(256) void norm_softmax_ip(u16* sc,
                                                       const float* __restrict__ stats,
                                                       int C) {
    int row = blockIdx.x;
    int plane = row / C;
    u16* x = sc + (size_t)row * 960;
    float mu = stats[2 * plane], rs = stats[2 * plane + 1];
    int t = threadIdx.x;
    bool act = t < 240;
    float v[4];
    float mx = -1e30f;
    if (act) {
        u16x4 d = *(const u16x4*)&x[t * 4];
#pragma unroll
        for (int j = 0; j < 4; j++) {
            v[j] = (bf2f(d[j]) - mu) * rs;
            mx = fmaxf(mx, v[j]);
        }
    }
    __shared__ float r1[4], r2[4];
#pragma unroll
    for (int o = 32; o; o >>= 1) mx = fmaxf(mx, __shfl_xor(mx, o));
    int w = t >> 6;
    if ((t & 63) == 0) r1[w] = mx;
    __syncthreads();
    mx = fmaxf(fmaxf(r1[0], r1[1]), fmaxf(r1[2], r1[3]));
    float s = 0.f;
    if (act) {
#pragma unroll
        for (int j = 0; j < 4; j++) {
            v[j] = __expf(v[j] - mx);
            s += v[j];
        }
    }
#pragma unroll
    for (int o = 32; o; o >>= 1) s += __shfl_xor(s, o);
    if ((t & 63) == 0) r2[w] = s;
    __syncthreads();
    s = r2[0] + r2[1] + r2[2] + r2[3];
    float inv = 1.0f / s;
    if (act) {
        u16x4 o;
#pragma unroll
        for (int j = 0; j < 4; j++) o[j] = f2bf(v[j] * inv);
        *(u16x4*)&x[t * 4] = o;
    }
}

// ---------------- head-mean + transpose (fallback path only) ----------------
__global__ __launch_bounds__(256) void mean_heads(const u16* __restrict__ ctx, long ps,
                                                  u16* __restrict__ cm, int C) {
    int b = blockIdx.z;
    int n0 = blockIdx.x * 64, c0 = blockIdx.y * 64;
    __shared__ float sm[64][65];
    int t = threadIdx.x;
    float acc[16];
#pragma unroll
    for (int j = 0; j < 16; j++) acc[j] = 0.f;
    for (int h = 0; h < 4; h++) {
        const u16* p = ctx + (size_t)(b * 4 + h) * ps;
#pragma unroll
        for (int j = 0; j < 16; j++) {
            int lin = j * 256 + t;
            int cc = lin >> 6, nn = lin & 63;
            acc[j] += bf2f(p[(size_t)(c0 + cc) * 1024 + n0 + nn]);
        }
    }
#pragma unroll
    for (int j = 0; j < 16; j++) {
        int lin = j * 256 + t;
        sm[lin >> 6][lin & 63] = acc[j] * 0.25f;
    }
    __syncthreads();
#pragma unroll
    for (int j = 0; j < 16; j++) {
        int lin = j * 256 + t;
        int nn = lin >> 6, cc = lin & 63;
        cm[((size_t)b * 1024 + n0 + nn) * C + c0 + cc] = f2bf(sm[cc][nn]);
    }
}

extern "C" void kernel_launch(void* const* d_in, const int* in_sizes, int n_in,
                              void* d_out, int out_size, void* d_ws, size_t ws_size,
                              hipStream_t stream) {
    const int B = 8, NN = 1024, KV = 960;
    const int Cs[4] = {64, 128, 256, 512};   // input order
    const int ord[4] = {3, 2, 1, 0};         // process 512,256,128,64 for row-concat
    const int offs[4] = {0, 512, 768, 896};  // row offset of ord[j] in the 960 space
    const float* emb[4];
    for (int i = 0; i < 4; i++) emb[i] = (const float*)d_in[i];
    const float* embAll = (const float*)d_in[4];
    const float* Wq[4];
    for (int i = 0; i < 4; i++) Wq[i] = (const float*)d_in[5 + i];
    const float* Wk = (const float*)d_in[9];
    const float* Wv = (const float*)d_in[10];
    const float* Wo[4];
    for (int i = 0; i < 4; i++) Wo[i] = (const float*)d_in[11 + i];
    float* out = (float*)d_out;
    size_t outOff[4];
    {
        size_t o = 0;
        for (int i = 0; i < 4; i++) { outOff[i] = o; o += (size_t)B * NN * Cs[i]; }
    }

    const size_t SKV = 62914560;  // 32*960*1024 bf16 (also fits VbCat 8*1024*3840, prCat 8*960*3840)
    const size_t SSC = 58982400;  // scores bf16 32*960*960
    const size_t SWQ = 2785280, SWO = 696320, SCM = 8388608;
    const size_t SPART = 131072, SST = 1024;
    const size_t SMALL = SWQ + SWO + SCM + SPART + SST;
    const size_t NEED_BAT = SSC + 3 * SKV + SMALL + 512;

    float invs = 1.0f / sqrtf((float)KV);
    auto g128 = [](int n) { return (n + 127) / 128; };

    if (ws_size >= NEED_BAT) {
        // ================= batched path =================
        char* p = (char*)d_ws;
        u16* scB = (u16*)p;        p += SSC;  // init: eA/wk/wv; then scores bf16; then cmCat
        u16* QtB = (u16*)p;        p += SKV;  // Qt_all [z][960][1024]; then prCat [b][960c][3840]
        u16* Kt = (u16*)p;         p += SKV;  // [z][960 j][1024 n]
        u16* VbC = (u16*)p;        p += SKV;  // VbCat [b][1024 n][3840 hk]
        u16* wq[4];
        for (int i = 0; i < 4; i++) { wq[i] = (u16*)p; p += (size_t)4 * Cs[i] * Cs[i] * 2; }
        u16* wo[4];
        for (int i = 0; i < 4; i++) { wo[i] = (u16*)p; p += (size_t)Cs[i] * Cs[i] * 2; }
        u16* cmX = (u16*)p;        p += SCM;
        double* part = (double*)p; p += SPART;
        float* stats = (float*)p;

        u16* eA = scB;
        u16* wk = (u16*)((char*)scB + 15728640);
        u16* wv = (u16*)((char*)scB + 23101440);
        u16* prB = QtB;   // alias: QtB dead after QK
        u16* cmC = scB;   // alias: scB dead after softmax

        auto castL = [&](const float* s, u16* d, size_t n) {
            int n4 = (int)(n / 4);
            cast_bf16<<<(n4 + 255) / 256, 256, 0, stream>>>((const float4*)s, (u16x4*)d, n4);
        };
        castL(embAll, eA, (size_t)B * NN * KV);
        castL(Wk, wk, (size_t)4 * KV * KV);
        castL(Wv, wv, (size_t)4 * KV * KV);
        for (int i = 0; i < 4; i++) castL(Wq[i], wq[i], (size_t)4 * Cs[i] * Cs[i]);
        for (int i = 0; i < 4; i++) castL(Wo[i], wo[i], (size_t)Cs[i] * Cs[i]);

        // Kt[z][j][n]
        gemm_nt128<u16><<<dim3(8, 8, 32), 256, 0, stream>>>(
            wk, 0, (long)KV * KV, KV, eA, (long)NN * KV, 0, KV,
            Kt, 4 * 983040L, 983040L, NN, KV, NN, KV, 4, 1.0f);
        // VbCat[b][n][h*960+j]
        gemm_nt128<u16><<<dim3(8, 8, 32), 256, 0, stream>>>(
            eA, (long)NN * KV, 0, KV, wv, 0, (long)KV * KV, KV,
            VbC, (long)NN * 3840, 960L, 3840, NN, KV, KV, 4, 1.0f);

        // Q-proj all branches into concatenated QtB rows
        for (int j = 0; j < 4; j++) {
            int i = ord[j], C = Cs[i];
            castL(emb[i], cmX, (size_t)B * NN * C);
            gemm_nt128<u16><<<dim3(8, g128(C), 32), 256, 0, stream>>>(
                wq[i], 0, (long)C * C, C, cmX, (long)NN * C, 0, C,
                QtB + (size_t)offs[j] * 1024, 4 * 983040L, 983040L, NN,
                C, NN, C, 4, 1.0f);
        }
        // one big QK: scB[z][960 c][960 k] bf16
        gemm_nt128<u16><<<dim3(8, 8, 32), 256, 0, stream>>>(
            QtB, 983040L, 0, NN, Kt, 983040L, 0, NN,
            scB, 921600L, 0, KV, 960, KV, NN, 1, invs);
        // instance-norm stats (128 planes) + softmax -> prCat
        in_stats1<<<dim3(16, 128), 256, 0, stream>>>(scB, part, 16, 1, 0);
        in_stats2<<<128, 64, 0, stream>>>(part, stats, 16, 1, 0);
        norm_softmax_cat<<<32 * 960, 256, 0, stream>>>(scB, stats, prB);
        // fused PV + head-mean: cmC[b][n][960 c] = 0.25 * sum_{hk} VbC[b][n][hk] * prB[b][c][hk]
        gemm_nt128<u16><<<dim3(8, 8, 8), 256, 0, stream>>>(
            VbC, (long)NN * 3840, 0, 3840, prB, (long)960 * 3840, 0, 3840,
            cmC, (long)NN * 960, 0, 960, NN, 960, 3840, 1, 0.25f);
        // out-proj per branch: out[b][n][c'] = sum_d cmC[b][n][offs_j+d] * Wo[c'][d]
        for (int j = 0; j < 4; j++) {
            int i = ord[j], C = Cs[i];
            gemm_nt128<float><<<dim3(g128(C), 8, 8), 256, 0, stream>>>(
                cmC + offs[j], (long)NN * 960, 0, 960, wo[i], 0, 0, C,
                out + outOff[i], (long)NN * C, 0, C, NN, C, C, 1, 1.0f);
        }
    } else {
        // ================= fallback per-branch path (~205 MB) =================
        const size_t S1 = 33554432, S2 = 33554432;
        if (ws_size < S1 + S2 + 2 * SKV + SMALL + 512) return;
        char* p = (char*)d_ws;
        char* buf1 = p;            p += S1;  // init eA/wk/wv -> sc(bf16)->probs in-place
        char* buf2 = p;            p += S2;  // Qt -> ctx
        u16* Kt = (u16*)p;         p += SKV;
        u16* Vb = (u16*)p;         p += SKV;
        u16* wq[4];
        for (int i = 0; i < 4; i++) { wq[i] = (u16*)p; p += (size_t)4 * Cs[i] * Cs[i] * 2; }
        u16* wo[4];
        for (int i = 0; i < 4; i++) { wo[i] = (u16*)p; p += (size_t)Cs[i] * Cs[i] * 2; }
        u16* cmX = (u16*)p;        p += SCM;
        double* part = (double*)p; p += SPART;
        float* stats = (float*)p;

        u16* eA = (u16*)buf1;
        u16* wk = (u16*)(buf1 + 15728640);
        u16* wv = (u16*)(buf1 + 23101440);
        u16* sc = (u16*)buf1;
        u16* Qt = (u16*)buf2;
        u16* ctx = (u16*)buf2;

        auto castL = [&](const float* s, u16* d, size_t n) {
            int n4 = (int)(n / 4);
            cast_bf16<<<(n4 + 255) / 256, 256, 0, stream>>>((const float4*)s, (u16x4*)d, n4);
        };
        castL(embAll, eA, (size_t)B * NN * KV);
        castL(Wk, wk, (size_t)4 * KV * KV);
        castL(Wv, wv, (size_t)4 * KV * KV);
        for (int i = 0; i < 4; i++) castL(Wq[i], wq[i], (size_t)4 * Cs[i] * Cs[i]);
        for (int i = 0; i < 4; i++) castL(Wo[i], wo[i], (size_t)Cs[i] * Cs[i]);

        gemm_nt128<u16><<<dim3(8, 8, 32), 256, 0, stream>>>(
            wk, 0, (long)KV * KV, KV, eA, (long)NN * KV, 0, KV,
            Kt, 4 * 983040L, 983040L, NN, KV, NN, KV, 4, 1.0f);
        gemm_nt128<u16><<<dim3(8, 8, 32), 256, 0, stream>>>(
            eA, (long)NN * KV, 0, KV, wv, 0, (long)KV * KV, KV,
            Vb, 4 * 983040L, 983040L, KV, NN, KV, KV, 4, 1.0f);

        for (int i = 0; i < 4; i++) {
            int C = Cs[i];
            castL(emb[i], cmX, (size_t)B * NN * C);
            gemm_nt128<u16><<<dim3(8, g128(C), 32), 256, 0, stream>>>(
                wq[i], 0, (long)C * C, C, cmX, (long)NN * C, 0, C,
                Qt, 4L * C * NN, (long)C * NN, NN, C, NN, C, 4, 1.0f);
            gemm_nt128<u16><<<dim3(8, g128(C), 32), 256, 0, stream>>>(
                Qt, (long)C * NN, 0, NN, Kt, 983040L, 0, NN,
                sc, (long)C * KV, 0, KV, C, KV, NN, 1, invs);
            in_stats1<<<dim3(64, 32), 256, 0, stream>>>(sc, part, 64, 0, C);
            in_stats2<<<32, 64, 0, stream>>>(part, stats, 64, 0, C);
            norm_softmax_ip<<<32 * C, 256, 0, stream>>>(sc, stats, C);
            gemm_nt128<u16><<<dim3(8, g128(C), 32), 256, 0, stream>>>(
                sc, (long)C * KV, 0, KV, Vb, 983040L, 0, KV,
                ctx, (long)C * NN, 0, NN, C, NN, KV, 1, 1.0f);
            mean_heads<<<dim3(16, C / 64, B), 256, 0, stream>>>(
                ctx, (long)C * NN, cmX, C);
            gemm_nt128<float><<<dim3(g128(C), 8, B), 256, 0, stream>>>(
                cmX, (long)NN * C, 0, C, wo[i], 0, 0, C,
                out + outOff[i], (long)NN * C, 0, C, NN, C, C, 1, 1.0f);
        }
    }
}

// Round 7
// 516.229 us; speedup vs baseline: 2.1993x; 1.2124x over previous
//
#include <hip/hip_runtime.h>
#include <stdint.h>

typedef unsigned short u16;
typedef short bf16x8 __attribute__((ext_vector_type(8)));
typedef float f32x4 __attribute__((ext_vector_type(4)));
typedef u16 u16x4 __attribute__((ext_vector_type(4)));

__device__ __forceinline__ u16 f2bf(float f) {
    unsigned u = __builtin_bit_cast(unsigned, f);
    unsigned r = (u + 0x7fffu + ((u >> 16) & 1u)) >> 16;
    return (u16)r;
}
__device__ __forceinline__ float bf2f(u16 h) {
    unsigned u = ((unsigned)h) << 16;
    return __builtin_bit_cast(float, u);
}

typedef const __attribute__((address_space(1))) unsigned int* gptr_t;
typedef __attribute__((address_space(3))) unsigned int* lptr_t;
__device__ __forceinline__ void gload16(const void* g, void* l) {
    __builtin_amdgcn_global_load_lds((gptr_t)(uintptr_t)g, (lptr_t)(uintptr_t)l, 16, 0, 0);
}

// branch tables: rows of the concatenated 960-row score/Q space
__device__ __constant__ int d_offs[4] = {0, 512, 768, 896};
__device__ __constant__ int d_cs[4] = {512, 256, 128, 64};

// ---------------- cast f32 -> bf16 (vectorized) ----------------
__global__ __launch_bounds__(256) void cast_bf16(const float4* __restrict__ in,
                                                 u16x4* __restrict__ out, int n4) {
    int i = blockIdx.x * 256 + threadIdx.x;
    if (i < n4) {
        float4 f = in[i];
        u16x4 o = {f2bf(f.x), f2bf(f.y), f2bf(f.z), f2bf(f.w)};
        out[i] = o;
    }
}

// ======== 2-phase double-buffered NT GEMM (T3 minimum-2ph recipe, m230) ========
// C[m,n] = alpha * sum_k A[m,k]*B[n,k], bf16 in, bf16 out.
// BM x BN tile, BK=64, TH threads (TH/64 waves in 2 x (TH/128) grid),
// per-wave output (BM/2) x 64. LDS = 2 buffers x (BM+BN)*64 bf16.
// Stage tile t+1 into buf[cur^1] BEFORE computing tile t from buf[cur];
// single __syncthreads per K-tile (compiler emits vmcnt(0) drain = recipe).
template <int BM, int BN, int TH>
__global__ __launch_bounds__(TH, 2) void gemm_nt_db(
    const u16* __restrict__ A, long sAb, long sAh, int lda,
    const u16* __restrict__ B, long sBb, long sBh, int ldb,
    u16* __restrict__ C, long sCb, long sCh, int ldc,
    int M, int N, int K, int hdiv, float alpha) {
    constexpr int WN = TH / 128;              // waves along N
    constexpr int WTM = BM / 2;               // per-wave M span
    constexpr int MF = WTM / 16;              // m-frags per wave
    constexpr int AISS = BM * 64 / (TH * 8);  // stage issues for A (=4)
    constexpr int BISS = BN * 64 / (TH * 8);  // stage issues for B (=4)
    constexpr int ASZ = BM * 64;              // A-tile elements
    __shared__ u16 lds[2][(BM + BN) * 64];

    // bijective XCD swizzle of the flat block id (m204)
    int gx = gridDim.x, gy = gridDim.y;
    int nwg = gx * gy * gridDim.z;
    int orig = blockIdx.x + gx * (blockIdx.y + gy * blockIdx.z);
    int q = nwg >> 3, r = nwg & 7;
    int xcd = orig & 7, seq = orig >> 3;
    int wg = (xcd < r ? xcd * (q + 1) : r * (q + 1) + (xcd - r) * q) + seq;
    int bx = wg % gx, tmpw = wg / gx;
    int by = tmpw % gy, bz = tmpw / gy;

    int bb = bz / hdiv, hh = bz - bb * hdiv;
    const u16* Ab = A + (size_t)bb * sAb + (size_t)hh * sAh;
    const u16* Bb = B + (size_t)bb * sBb + (size_t)hh * sBh;
    u16* Cb = C + (size_t)bb * sCb + (size_t)hh * sCh;
    int tm = by * BM, tn = bx * BN;
    int t = threadIdx.x, lane = t & 63, w = t >> 6;
    int wm = w / WN, wn = w % WN;

    // hoisted, clamped staging source pointers (advance by 64 per staged tile)
    const u16* gA[AISS];
    const u16* gB[BISS];
#pragma unroll
    for (int i = 0; i < AISS; i++) {
        int seg = i * TH + t;
        int row = tm + (seg >> 3);
        if (row > M - 1) row = M - 1;
        gA[i] = Ab + (size_t)row * lda + (seg & 7) * 8;
    }
#pragma unroll
    for (int i = 0; i < BISS; i++) {
        int seg = i * TH + t;
        int row = tn + (seg >> 3);
        if (row > N - 1) row = N - 1;
        gB[i] = Bb + (size_t)row * ldb + (seg & 7) * 8;
    }

    auto stage = [&](int bi) {
#pragma unroll
        for (int i = 0; i < AISS; i++) {
            gload16(gA[i], &lds[bi][(i * TH + t) * 8]);
            gA[i] += 64;
        }
#pragma unroll
        for (int i = 0; i < BISS; i++) {
            gload16(gB[i], &lds[bi][ASZ + (i * TH + t) * 8]);
            gB[i] += 64;
        }
    };

    f32x4 acc[MF][4] = {};
    int la = lane & 15, lk = (lane >> 4) * 8;
    int nt = K / 64;
    // prologue: stage tile 0 into buf 0, drain, barrier
    stage(0);
    __syncthreads();
    int cur = 0;
    for (int tt = 0; tt < nt; ++tt) {
        if (tt + 1 < nt) stage(cur ^ 1);  // issue next tile's loads first
#pragma unroll
        for (int kk = 0; kk < 64; kk += 32) {
            bf16x8 a[MF], b[4];
#pragma unroll
            for (int mi = 0; mi < MF; mi++)
                a[mi] = *(const bf16x8*)&lds[cur][(wm * WTM + mi * 16 + la) * 64 + kk + lk];
#pragma unroll
            for (int ni = 0; ni < 4; ni++)
                b[ni] = *(const bf16x8*)&lds[cur][ASZ + (wn * 64 + ni * 16 + la) * 64 + kk + lk];
            __builtin_amdgcn_s_setprio(1);
#pragma unroll
            for (int mi = 0; mi < MF; mi++)
#pragma unroll
                for (int ni = 0; ni < 4; ni++)
                    acc[mi][ni] = __builtin_amdgcn_mfma_f32_16x16x32_bf16(
                        a[mi], b[ni], acc[mi][ni], 0, 0, 0);
            __builtin_amdgcn_s_setprio(0);
        }
        __syncthreads();  // vmcnt(0)+lgkmcnt(0) drain + barrier: next tile landed
        cur ^= 1;
    }
#pragma unroll
    for (int mi = 0; mi < MF; mi++)
#pragma unroll
        for (int ni = 0; ni < 4; ni++)
#pragma unroll
            for (int r_ = 0; r_ < 4; r_++) {
                int m = tm + wm * WTM + mi * 16 + (lane >> 4) * 4 + r_;
                int n = tn + wn * 64 + ni * 16 + la;
                if (m < M && n < N)
                    Cb[(size_t)m * ldc + n] = f2bf(acc[mi][ni][r_] * alpha);
            }
}

// ---------------- NT GEMM (m97 1-phase, 128 tile) for small GEMMs + fallback ----------------
template <typename OUT>
__global__ __launch_bounds__(256) void gemm_nt128(
    const u16* __restrict__ A, long sAb, long sAh, int lda,
    const u16* __restrict__ B, long sBb, long sBh, int ldb,
    OUT* __restrict__ C, long sCb, long sCh, int ldc,
    int M, int N, int K, int hdiv, float alpha) {
    __shared__ u16 sA[128 * 64];
    __shared__ u16 sB[128 * 64];
    int gx = gridDim.x, gy = gridDim.y;
    int nwg = gx * gy * gridDim.z;
    int orig = blockIdx.x + gx * (blockIdx.y + gy * blockIdx.z);
    int q = nwg >> 3, r = nwg & 7;
    int xcd = orig & 7, seq = orig >> 3;
    int wg = (xcd < r ? xcd * (q + 1) : r * (q + 1) + (xcd - r) * q) + seq;
    int bx = wg % gx, tmpw = wg / gx;
    int by = tmpw % gy, bz = tmpw / gy;

    int bb = bz / hdiv, hh = bz - bb * hdiv;
    const u16* Ab = A + (size_t)bb * sAb + (size_t)hh * sAh;
    const u16* Bb = B + (size_t)bb * sBb + (size_t)hh * sBh;
    OUT* Cb = C + (size_t)bb * sCb + (size_t)hh * sCh;
    int tm = by * 128, tn = bx * 128;
    int t = threadIdx.x, lane = t & 63, w = t >> 6;
    int wr = w >> 1, wc = w & 1;
    int r0 = t >> 3, c0 = (t & 7) * 8;
    const u16* gA[4];
    const u16* gB[4];
#pragma unroll
    for (int i = 0; i < 4; i++) {
        int ar = tm + i * 32 + r0;
        if (ar > M - 1) ar = M - 1;
        gA[i] = Ab + (size_t)ar * lda + c0;
    }
#pragma unroll
    for (int i = 0; i < 4; i++) {
        int br = tn + i * 32 + r0;
        if (br > N - 1) br = N - 1;
        gB[i] = Bb + (size_t)br * ldb + c0;
    }
    f32x4 acc[4][4] = {};
    int la = lane & 15, lk = (lane >> 4) * 8;
    for (int k0 = 0; k0 < K; k0 += 64) {
#pragma unroll
        for (int i = 0; i < 4; i++) {
            gload16(gA[i], &sA[(i * 256 + t) * 8]);
            gA[i] += 64;
        }
#pragma unroll
        for (int i = 0; i < 4; i++) {
            gload16(gB[i], &sB[(i * 256 + t) * 8]);
            gB[i] += 64;
        }
        __syncthreads();
#pragma unroll
        for (int kk = 0; kk < 64; kk += 32) {
            bf16x8 a[4], b[4];
#pragma unroll
            for (int mi = 0; mi < 4; mi++)
                a[mi] = *(const bf16x8*)&sA[(wr * 64 + mi * 16 + la) * 64 + kk + lk];
#pragma unroll
            for (int ni = 0; ni < 4; ni++)
                b[ni] = *(const bf16x8*)&sB[(wc * 64 + ni * 16 + la) * 64 + kk + lk];
#pragma unroll
            for (int mi = 0; mi < 4; mi++)
#pragma unroll
                for (int ni = 0; ni < 4; ni++)
                    acc[mi][ni] = __builtin_amdgcn_mfma_f32_16x16x32_bf16(
                        a[mi], b[ni], acc[mi][ni], 0, 0, 0);
        }
        __syncthreads();
    }
#pragma unroll
    for (int mi = 0; mi < 4; mi++)
#pragma unroll
        for (int ni = 0; ni < 4; ni++)
#pragma unroll
            for (int r_ = 0; r_ < 4; r_++) {
                int m = tm + wr * 64 + mi * 16 + (lane >> 4) * 4 + r_;
                int n = tn + wc * 64 + ni * 16 + la;
                if (m < M && n < N) {
                    float v = acc[mi][ni][r_] * alpha;
                    if constexpr (sizeof(OUT) == 4)
                        Cb[(size_t)m * ldc + n] = v;
                    else
                        Cb[(size_t)m * ldc + n] = f2bf(v);
                }
            }
}

// ---------------- instance-norm stats, stage 1 (bf16 input, two-stage deterministic) ----------------
__global__ __launch_bounds__(256) void in_stats1(const u16* __restrict__ sc,
                                                 double* __restrict__ part,
                                                 int G, int mode, int C) {
    int p = blockIdx.y, g = blockIdx.x, t = threadIdx.x;
    size_t base;
    int n8;
    if (mode) {
        int z = p >> 2, i = p & 3;
        base = (size_t)z * 921600 + (size_t)d_offs[i] * 960;
        n8 = d_cs[i] * 120;
    } else {
        base = (size_t)p * C * 960;
        n8 = C * 120;
    }
    const u16* x = sc + base;
    double s = 0.0, q = 0.0;
    for (int i = g * 256 + t; i < n8; i += G * 256) {
        u16x4 a = *(const u16x4*)&x[i * 8];
        u16x4 b = *(const u16x4*)&x[i * 8 + 4];
#pragma unroll
        for (int j = 0; j < 4; j++) {
            float fa = bf2f(a[j]), fb = bf2f(b[j]);
            s += (double)fa + (double)fb;
            q += (double)fa * fa + (double)fb * fb;
        }
    }
#pragma unroll
    for (int o = 32; o; o >>= 1) {
        s += __shfl_down(s, o);
        q += __shfl_down(q, o);
    }
    __shared__ double rs[4], rq[4];
    int w = t >> 6;
    if ((t & 63) == 0) {
        rs[w] = s;
        rq[w] = q;
    }
    __syncthreads();
    if (t == 0) {
        part[2 * ((size_t)p * G + g)] = rs[0] + rs[1] + rs[2] + rs[3];
        part[2 * ((size_t)p * G + g) + 1] = rq[0] + rq[1] + rq[2] + rq[3];
    }
}

// ---------------- stage 2: reduce G partials per plane -> mu, rsqrt(var+eps) ----------------
__global__ __launch_bounds__(64) void in_stats2(const double* __restrict__ part,
                                                float* __restrict__ stats,
                                                int G, int mode, int C) {
    int p = blockIdx.x, t = threadIdx.x;
    int cnt = (mode ? d_cs[p & 3] : C) * 960;
    double s = 0.0, q = 0.0;
    if (t < G) {
        s = part[2 * ((size_t)p * G + t)];
        q = part[2 * ((size_t)p * G + t) + 1];
    }
#pragma unroll
    for (int o = 32; o; o >>= 1) {
        s += __shfl_down(s, o);
        q += __shfl_down(q, o);
    }
    if (t == 0) {
        float mu = (float)(s / cnt);
        float var = (float)(q / cnt) - mu * mu;
        stats[2 * p] = mu;
        stats[2 * p + 1] = rsqrtf(var + 1e-5f);
    }
}

// ---------------- normalize + softmax -> prCat[b][c][h*960+k] (batched path) ----------------
__global__ __launch_bounds__(256) void norm_softmax_cat(const u16* __restrict__ sc,
                                                        const float* __restrict__ stats,
                                                        u16* __restrict__ prB) {
    int row = blockIdx.x;  // [0, 32*960): z*960 + c
    int z = row / 960, c = row - z * 960;
    int i = c < 512 ? 0 : (c < 768 ? 1 : (c < 896 ? 2 : 3));
    int plane = z * 4 + i;
    int b = z >> 2, h = z & 3;
    const u16* x = sc + (size_t)row * 960;
    u16* o = prB + (((size_t)b * 960 + c) * 4 + h) * 960;
    float mu = stats[2 * plane], rs = stats[2 * plane + 1];
    int t = threadIdx.x;
    bool act = t < 240;
    float v[4];
    float mx = -1e30f;
    if (act) {
        u16x4 d = *(const u16x4*)&x[t * 4];
#pragma unroll
        for (int j = 0; j < 4; j++) {
            v[j] = (bf2f(d[j]) - mu) * rs;
            mx = fmaxf(mx, v[j]);
        }
    }
    __shared__ float r1[4], r2[4];
#pragma unroll
    for (int o_ = 32; o_; o_ >>= 1) mx = fmaxf(mx, __shfl_xor(mx, o_));
    int w = t >> 6;
    if ((t & 63) == 0) r1[w] = mx;
    __syncthreads();
    mx = fmaxf(fmaxf(r1[0], r1[1]), fmaxf(r1[2], r1[3]));
    float s = 0.f;
    if (act) {
#pragma unroll
        for (int j = 0; j < 4; j++) {
            v[j] = __expf(v[j] - mx);
            s += v[j];
        }
    }
#pragma unroll
    for (int o_ = 32; o_; o_ >>= 1) s += __shfl_xor(s, o_);
    if ((t & 63) == 0) r2[w] = s;
    __syncthreads();
    s = r2[0] + r2[1] + r2[2] + r2[3];
    float inv = 1.0f / s;
    if (act) {
        u16x4 ov;
#pragma unroll
        for (int j = 0; j < 4; j++) ov[j] = f2bf(v[j] * inv);
        *(u16x4*)&o[t * 4] = ov;
    }
}

// ---------------- normalize + softmax, in-place (fallback path) ----------------
__global__ __launch_bounds__(256) void norm_softmax_ip(u16* sc,
                                                       const float* __restrict__ stats,
                                                       int C) {
    int row = blockIdx.x;
    int plane = row / C;
    u16* x = sc + (size_t)row * 960;
    float mu = stats[2 * plane], rs = stats[2 * plane + 1];
    int t = threadIdx.x;
    bool act = t < 240;
    float v[4];
    float mx = -1e30f;
    if (act) {
        u16x4 d = *(const u16x4*)&x[t * 4];
#pragma unroll
        for (int j = 0; j < 4; j++) {
            v[j] = (bf2f(d[j]) - mu) * rs;
            mx = fmaxf(mx, v[j]);
        }
    }
    __shared__ float r1[4], r2[4];
#pragma unroll
    for (int o = 32; o; o >>= 1) mx = fmaxf(mx, __shfl_xor(mx, o));
    int w = t >> 6;
    if ((t & 63) == 0) r1[w] = mx;
    __syncthreads();
    mx = fmaxf(fmaxf(r1[0], r1[1]), fmaxf(r1[2], r1[3]));
    float s = 0.f;
    if (act) {
#pragma unroll
        for (int j = 0; j < 4; j++) {
            v[j] = __expf(v[j] - mx);
            s += v[j];
        }
    }
#pragma unroll
    for (int o = 32; o; o >>= 1) s += __shfl_xor(s, o);
    if ((t & 63) == 0) r2[w] = s;
    __syncthreads();
    s = r2[0] + r2[1] + r2[2] + r2[3];
    float inv = 1.0f / s;
    if (act) {
        u16x4 o;
#pragma unroll
        for (int j = 0; j < 4; j++) o[j] = f2bf(v[j] * inv);
        *(u16x4*)&x[t * 4] = o;
    }
}

// ---------------- head-mean + transpose (fallback path only) ----------------
__global__ __launch_bounds__(256) void mean_heads(const u16* __restrict__ ctx, long ps,
                                                  u16* __restrict__ cm, int C) {
    int b = blockIdx.z;
    int n0 = blockIdx.x * 64, c0 = blockIdx.y * 64;
    __shared__ float sm[64][65];
    int t = threadIdx.x;
    float acc[16];
#pragma unroll
    for (int j = 0; j < 16; j++) acc[j] = 0.f;
    for (int h = 0; h < 4; h++) {
        const u16* p = ctx + (size_t)(b * 4 + h) * ps;
#pragma unroll
        for (int j = 0; j < 16; j++) {
            int lin = j * 256 + t;
            int cc = lin >> 6, nn = lin & 63;
            acc[j] += bf2f(p[(size_t)(c0 + cc) * 1024 + n0 + nn]);
        }
    }
#pragma unroll
    for (int j = 0; j < 16; j++) {
        int lin = j * 256 + t;
        sm[lin >> 6][lin & 63] = acc[j] * 0.25f;
    }
    __syncthreads();
#pragma unroll
    for (int j = 0; j < 16; j++) {
        int lin = j * 256 + t;
        int nn = lin >> 6, cc = lin & 63;
        cm[((size_t)b * 1024 + n0 + nn) * C + c0 + cc] = f2bf(sm[cc][nn]);
    }
}

extern "C" void kernel_launch(void* const* d_in, const int* in_sizes, int n_in,
                              void* d_out, int out_size, void* d_ws, size_t ws_size,
                              hipStream_t stream) {
    const int B = 8, NN = 1024, KV = 960;
    const int Cs[4] = {64, 128, 256, 512};   // input order
    const int ord[4] = {3, 2, 1, 0};         // process 512,256,128,64 for row-concat
    const int offs[4] = {0, 512, 768, 896};  // row offset of ord[j] in the 960 space
    const float* emb[4];
    for (int i = 0; i < 4; i++) emb[i] = (const float*)d_in[i];
    const float* embAll = (const float*)d_in[4];
    const float* Wq[4];
    for (int i = 0; i < 4; i++) Wq[i] = (const float*)d_in[5 + i];
    const float* Wk = (const float*)d_in[9];
    const float* Wv = (const float*)d_in[10];
    const float* Wo[4];
    for (int i = 0; i < 4; i++) Wo[i] = (const float*)d_in[11 + i];
    float* out = (float*)d_out;
    size_t outOff[4];
    {
        size_t o = 0;
        for (int i = 0; i < 4; i++) { outOff[i] = o; o += (size_t)B * NN * Cs[i]; }
    }

    const size_t SKV = 62914560;  // 32*960*1024 bf16 (fits VbCat 8*1024*3840, prCat 8*960*3840)
    const size_t SSC = 58982400;  // scores bf16 32*960*960
    const size_t SWQ = 2785280, SWO = 696320, SCM = 8388608;
    const size_t SPART = 131072, SST = 1024;
    const size_t SMALL = SWQ + SWO + SCM + SPART + SST;
    const size_t NEED_BAT = SSC + 3 * SKV + SMALL + 512;

    float invs = 1.0f / sqrtf((float)KV);
    auto g128 = [](int n) { return (n + 127) / 128; };

    if (ws_size >= NEED_BAT) {
        // ================= batched path =================
        char* p = (char*)d_ws;
        u16* scB = (u16*)p;        p += SSC;  // init: eA/wk/wv; then scores bf16; then cmCat
        u16* QtB = (u16*)p;        p += SKV;  // Qt_all [z][960][1024]; then prCat [b][960c][3840]
        u16* Kt = (u16*)p;         p += SKV;  // [z][960 j][1024 n]
        u16* VbC = (u16*)p;        p += SKV;  // VbCat [b][1024 n][3840 hk]
        u16* wq[4];
        for (int i = 0; i < 4; i++) { wq[i] = (u16*)p; p += (size_t)4 * Cs[i] * Cs[i] * 2; }
        u16* wo[4];
        for (int i = 0; i < 4; i++) { wo[i] = (u16*)p; p += (size_t)Cs[i] * Cs[i] * 2; }
        u16* cmX = (u16*)p;        p += SCM;
        double* part = (double*)p; p += SPART;
        float* stats = (float*)p;

        u16* eA = scB;
        u16* wk = (u16*)((char*)scB + 15728640);
        u16* wv = (u16*)((char*)scB + 23101440);
        u16* prB = QtB;  // alias: QtB dead after QK
        u16* cmC = scB;  // alias: scB dead after softmax

        auto castL = [&](const float* s, u16* d, size_t n) {
            int n4 = (int)(n / 4);
            cast_bf16<<<(n4 + 255) / 256, 256, 0, stream>>>((const float4*)s, (u16x4*)d, n4);
        };
        castL(embAll, eA, (size_t)B * NN * KV);
        castL(Wk, wk, (size_t)4 * KV * KV);
        castL(Wv, wv, (size_t)4 * KV * KV);
        for (int i = 0; i < 4; i++) castL(Wq[i], wq[i], (size_t)4 * Cs[i] * Cs[i]);
        for (int i = 0; i < 4; i++) castL(Wo[i], wo[i], (size_t)Cs[i] * Cs[i]);

        // Kt[z][j][n]  (2-phase 256^2)
        gemm_nt_db<256, 256, 512><<<dim3(4, 4, 32), 512, 0, stream>>>(
            wk, 0, (long)KV * KV, KV, eA, (long)NN * KV, 0, KV,
            Kt, 4 * 983040L, 983040L, NN, KV, NN, KV, 4, 1.0f);
        // VbCat[b][n][h*960+j]  (2-phase 256^2)
        gemm_nt_db<256, 256, 512><<<dim3(4, 4, 32), 512, 0, stream>>>(
            eA, (long)NN * KV, 0, KV, wv, 0, (long)KV * KV, KV,
            VbC, (long)NN * 3840, 960L, 3840, NN, KV, KV, 4, 1.0f);

        // Q-proj all branches into concatenated QtB rows (small GEMMs, 1-phase 128^2)
        for (int j = 0; j < 4; j++) {
            int i = ord[j], C = Cs[i];
            castL(emb[i], cmX, (size_t)B * NN * C);
            gemm_nt128<u16><<<dim3(8, g128(C), 32), 256, 0, stream>>>(
                wq[i], 0, (long)C * C, C, cmX, (long)NN * C, 0, C,
                QtB + (size_t)offs[j] * 1024, 4 * 983040L, 983040L, NN,
                C, NN, C, 4, 1.0f);
        }
        // one big QK: scB[z][960 c][960 k] bf16  (2-phase 256^2)
        gemm_nt_db<256, 256, 512><<<dim3(4, 4, 32), 512, 0, stream>>>(
            QtB, 983040L, 0, NN, Kt, 983040L, 0, NN,
            scB, 921600L, 0, KV, 960, KV, NN, 1, invs);
        // instance-norm stats (128 planes) + softmax -> prCat
        in_stats1<<<dim3(16, 128), 256, 0, stream>>>(scB, part, 16, 1, 0);
        in_stats2<<<128, 64, 0, stream>>>(part, stats, 16, 1, 0);
        norm_softmax_cat<<<32 * 960, 256, 0, stream>>>(scB, stats, prB);
        // fused PV + head-mean (2-phase 128^2, z=8 -> 512 blocks):
        // cmC[b][n][960 c] = 0.25 * sum_{hk} VbC[b][n][hk] * prB[b][c][hk]
        gemm_nt_db<128, 128, 256><<<dim3(8, 8, 8), 256, 0, stream>>>(
            VbC, (long)NN * 3840, 0, 3840, prB, (long)960 * 3840, 0, 3840,
            cmC, (long)NN * 960, 0, 960, NN, 960, 3840, 1, 0.25f);
        // out-proj per branch
        for (int j = 0; j < 4; j++) {
            int i = ord[j], C = Cs[i];
            gemm_nt128<float><<<dim3(g128(C), 8, 8), 256, 0, stream>>>(
                cmC + offs[j], (long)NN * 960, 0, 960, wo[i], 0, 0, C,
                out + outOff[i], (long)NN * C, 0, C, NN, C, C, 1, 1.0f);
        }
    } else {
        // ================= fallback per-branch path (~205 MB) =================
        const size_t S1 = 33554432, S2 = 33554432;
        if (ws_size < S1 + S2 + 2 * SKV + SMALL + 512) return;
        char* p = (char*)d_ws;
        char* buf1 = p;            p += S1;
        char* buf2 = p;            p += S2;
        u16* Kt = (u16*)p;         p += SKV;
        u16* Vb = (u16*)p;         p += SKV;
        u16* wq[4];
        for (int i = 0; i < 4; i++) { wq[i] = (u16*)p; p += (size_t)4 * Cs[i] * Cs[i] * 2; }
        u16* wo[4];
        for (int i = 0; i < 4; i++) { wo[i] = (u16*)p; p += (size_t)Cs[i] * Cs[i] * 2; }
        u16* cmX = (u16*)p;        p += SCM;
        double* part = (double*)p; p += SPART;
        float* stats = (float*)p;

        u16* eA = (u16*)buf1;
        u16* wk = (u16*)(buf1 + 15728640);
        u16* wv = (u16*)(buf1 + 23101440);
        u16* sc = (u16*)buf1;
        u16* Qt = (u16*)buf2;
        u16* ctx = (u16*)buf2;

        auto castL = [&](const float* s, u16* d, size_t n) {
            int n4 = (int)(n / 4);
            cast_bf16<<<(n4 + 255) / 256, 256, 0, stream>>>((const float4*)s, (u16x4*)d, n4);
        };
        castL(embAll, eA, (size_t)B * NN * KV);
        castL(Wk, wk, (size_t)4 * KV * KV);
        castL(Wv, wv, (size_t)4 * KV * KV);
        for (int i = 0; i < 4; i++) castL(Wq[i], wq[i], (size_t)4 * Cs[i] * Cs[i]);
        for (int i = 0; i < 4; i++) castL(Wo[i], wo[i], (size_t)Cs[i] * Cs[i]);

        gemm_nt128<u16><<<dim3(8, 8, 32), 256, 0, stream>>>(
            wk, 0, (long)KV * KV, KV, eA, (long)NN * KV, 0, KV,
            Kt, 4 * 983040L, 983040L, NN, KV, NN, KV, 4, 1.0f);
        gemm_nt128<u16><<<dim3(8, 8, 32), 256, 0, stream>>>(
            eA, (long)NN * KV, 0, KV, wv, 0, (long)KV * KV, KV,
            Vb, 4 * 983040L, 983040L, KV, NN, KV, KV, 4, 1.0f);

        for (int i = 0; i < 4; i++) {
            int C = Cs[i];
            castL(emb[i], cmX, (size_t)B * NN * C);
            gemm_nt128<u16><<<dim3(8, g128(C), 32), 256, 0, stream>>>(
                wq[i], 0, (long)C * C, C, cmX, (long)NN * C, 0, C,
                Qt, 4L * C * NN, (long)C * NN, NN, C, NN, C, 4, 1.0f);
            gemm_nt128<u16><<<dim3(8, g128(C), 32), 256, 0, stream>>>(
                Qt, (long)C * NN, 0, NN, Kt, 983040L, 0, NN,
                sc, (long)C * KV, 0, KV, C, KV, NN, 1, invs);
            in_stats1<<<dim3(64, 32), 256, 0, stream>>>(sc, part, 64, 0, C);
            in_stats2<<<32, 64, 0, stream>>>(part, stats, 64, 0, C);
            norm_softmax_ip<<<32 * C, 256, 0, stream>>>(sc, stats, C);
            gemm_nt128<u16><<<dim3(8, g128(C), 32), 256, 0, stream>>>(
                sc, (long)C * KV, 0, KV, Vb, 983040L, 0, KV,
                ctx, (long)C * NN, 0, NN, C, NN, KV, 1, 1.0f);
            mean_heads<<<dim3(16, C / 64, B), 256, 0, stream>>>(
                ctx, (long)C * NN, cmX, C);
            gemm_nt128<float><<<dim3(g128(C), 8, B), 256, 0, stream>>>(
                cmX, (long)NN * C, 0, C, wo[i], 0, 0, C,
                out + outOff[i], (long)NN * C, 0, C, NN, C, C, 1, 1.0f);
        }
    }
}

// Round 8
// 482.171 us; speedup vs baseline: 2.3546x; 1.0706x over previous
//
#include <hip/hip_runtime.h>
#include <stdint.h>

typedef unsigned short u16;
typedef short bf16x8 __attribute__((ext_vector_type(8)));
typedef float f32x4 __attribute__((ext_vector_type(4)));
typedef u16 u16x4 __attribute__((ext_vector_type(4)));

__device__ __forceinline__ u16 f2bf(float f) {
    unsigned u = __builtin_bit_cast(unsigned, f);
    unsigned r = (u + 0x7fffu + ((u >> 16) & 1u)) >> 16;
    return (u16)r;
}
__device__ __forceinline__ float bf2f(u16 h) {
    unsigned u = ((unsigned)h) << 16;
    return __builtin_bit_cast(float, u);
}

typedef const __attribute__((address_space(1))) unsigned int* gptr_t;
typedef __attribute__((address_space(3))) unsigned int* lptr_t;
__device__ __forceinline__ void gload16(const void* g, void* l) {
    __builtin_amdgcn_global_load_lds((gptr_t)(uintptr_t)g, (lptr_t)(uintptr_t)l, 16, 0, 0);
}

// branch tables: rows of the concatenated 960-row score/Q space
__device__ __constant__ int d_offs[4] = {0, 512, 768, 896};
__device__ __constant__ int d_cs[4] = {512, 256, 128, 64};

// ---------------- cast f32 -> bf16 (vectorized) ----------------
__global__ __launch_bounds__(256) void cast_bf16(const float4* __restrict__ in,
                                                 u16x4* __restrict__ out, int n4) {
    int i = blockIdx.x * 256 + threadIdx.x;
    if (i < n4) {
        float4 f = in[i];
        u16x4 o = {f2bf(f.x), f2bf(f.y), f2bf(f.z), f2bf(f.w)};
        out[i] = o;
    }
}

// ======== 8-phase counted-vmcnt NT GEMM (m201-style, T2 swizzle, T5) ========
// C[m,n] = alpha * sum_k A[m,k]*B[n,k]; bf16 in/out. BN=256 fixed, BM in {256,128}.
// 512 threads = 8 waves (wm = w>>2 in {0,1}, wn = w&3). Per-wave out: (BM/2) x 64.
// LDS: 2 bufs x {A0,A1 (BM/2 x 64 each), B0,B1 (128 x 64 each)} parts.
// Per K-tile k (4 phases): B reg-loaded fully at p0 (B parts die at p0);
// A-half wm read one 32-row quadrant per phase. Stage: A0(k+1)@p0, A1(k+1)@p1
// into buf[k+1]; B0(k+2)@p2, B1(k+2)@p3 into CURRENT buf's dead B slots.
// One counted vmcnt(4) per tile at end of p3, BEFORE the boundary barrier.
// T2 swizzle: phys_slot = logical_slot ^ (row&7), applied on global SOURCE
// (inverse) + ds_read (rule #21); gload_lds dest stays linear.
#define AREAD(P)                                                                   \
    bf16x8 areg[MFP][2];                                                           \
    _Pragma("unroll") for (int f = 0; f < MFP; f++)                                \
        _Pragma("unroll") for (int kb = 0; kb < 2; kb++) {                         \
            int rl = ((P)*MFP + f) * 16 + la;                                      \
            areg[f][kb] = *(const bf16x8*)&lds[ao + rl * 64 +                      \
                                               (((kb * 4 + lk4) ^ (rl & 7)) << 3)]; \
        }
#define CLUSTER(P)                                                                 \
    __builtin_amdgcn_s_barrier();                                                  \
    asm volatile("s_waitcnt lgkmcnt(0)" ::: "memory");                             \
    __builtin_amdgcn_sched_barrier(0);                                             \
    __builtin_amdgcn_s_setprio(1);                                                 \
    _Pragma("unroll") for (int f = 0; f < MFP; f++)                                \
        _Pragma("unroll") for (int ni = 0; ni < 4; ni++)                           \
            _Pragma("unroll") for (int kb = 0; kb < 2; kb++)                       \
                acc[(P)*MFP + f][ni] = __builtin_amdgcn_mfma_f32_16x16x32_bf16(    \
                    areg[f][kb], breg[ni][kb], acc[(P)*MFP + f][ni], 0, 0, 0);     \
    __builtin_amdgcn_s_setprio(0);

template <int BM>
__global__ __launch_bounds__(512, 2) void gemm_nt_8ph(
    const u16* __restrict__ A, long sAb, long sAh, int lda,
    const u16* __restrict__ B, long sBb, long sBh, int ldb,
    u16* __restrict__ C, long sCb, long sCh, int ldc,
    int M, int N, int K, int hdiv, float alpha) {
    constexpr int NA = BM / 128;     // gload_lds per thread per A-half stage
    constexpr int MFP = BM / 128;    // m-frags per phase
    constexpr int WTM = BM / 2;      // per-wave rows
    constexpr int NMF = WTM / 16;    // m-frags per wave
    constexpr int APART = WTM * 64;  // u16 per A half
    constexpr int BPART = 128 * 64;
    constexpr int BUFSZ = 2 * APART + 2 * BPART;
    __shared__ u16 lds[2 * BUFSZ];

    // bijective XCD swizzle (m204)
    int gx = gridDim.x, gy = gridDim.y;
    int nwg = gx * gy * gridDim.z;
    int orig = blockIdx.x + gx * (blockIdx.y + gy * blockIdx.z);
    int q = nwg >> 3, r = nwg & 7;
    int xcd = orig & 7, seq = orig >> 3;
    int wg = (xcd < r ? xcd * (q + 1) : r * (q + 1) + (xcd - r) * q) + seq;
    int bx = wg % gx, tmpw = wg / gx;
    int by = tmpw % gy, bz = tmpw / gy;

    int bb = bz / hdiv, hh = bz - bb * hdiv;
    const u16* Ab = A + (size_t)bb * sAb + (size_t)hh * sAh;
    const u16* Bb = B + (size_t)bb * sBb + (size_t)hh * sBh;
    u16* Cb = C + (size_t)bb * sCb + (size_t)hh * sCh;
    int tm = by * BM, tn = bx * 256;
    int t = threadIdx.x, lane = t & 63, w = t >> 6;
    int wm = w >> 2, wn = w & 3;
    int la = lane & 15, lk4 = lane >> 4;

    // staging source pointers: inverse-swizzled col, clamped rows; +=64/tile
    const u16* pA0[NA];
    const u16* pA1[NA];
    const u16* pB0[2];
    const u16* pB1[2];
#pragma unroll
    for (int i = 0; i < NA; i++) {
        int seg = i * 512 + t;
        int col = (((seg & 7) ^ ((seg >> 3) & 7)) << 3);
        int r0 = tm + (seg >> 3);
        if (r0 > M - 1) r0 = M - 1;
        pA0[i] = Ab + (size_t)r0 * lda + col;
        int r1 = tm + WTM + (seg >> 3);
        if (r1 > M - 1) r1 = M - 1;
        pA1[i] = Ab + (size_t)r1 * lda + col;
    }
#pragma unroll
    for (int i = 0; i < 2; i++) {
        int seg = i * 512 + t;
        int col = (((seg & 7) ^ ((seg >> 3) & 7)) << 3);
        int r0 = tn + (seg >> 3);
        if (r0 > N - 1) r0 = N - 1;
        pB0[i] = Bb + (size_t)r0 * ldb + col;
        int r1 = tn + 128 + (seg >> 3);
        if (r1 > N - 1) r1 = N - 1;
        pB1[i] = Bb + (size_t)r1 * ldb + col;
    }

    auto AOF = [&](int buf, int h) { return buf * BUFSZ + h * APART; };
    auto BOF = [&](int buf, int h) { return buf * BUFSZ + 2 * APART + h * BPART; };
    auto stA0 = [&](int buf) {
#pragma unroll
        for (int i = 0; i < NA; i++) {
            gload16(pA0[i], &lds[AOF(buf, 0) + (i * 512 + t) * 8]);
            pA0[i] += 64;
        }
    };
    auto stA1 = [&](int buf) {
#pragma unroll
        for (int i = 0; i < NA; i++) {
            gload16(pA1[i], &lds[AOF(buf, 1) + (i * 512 + t) * 8]);
            pA1[i] += 64;
        }
    };
    auto stB0 = [&](int buf) {
#pragma unroll
        for (int i = 0; i < 2; i++) {
            gload16(pB0[i], &lds[BOF(buf, 0) + (i * 512 + t) * 8]);
            pB0[i] += 64;
        }
    };
    auto stB1 = [&](int buf) {
#pragma unroll
        for (int i = 0; i < 2; i++) {
            gload16(pB1[i], &lds[BOF(buf, 1) + (i * 512 + t) * 8]);
            pB1[i] += 64;
        }
    };

    int nt = K / 64;
    // prologue: tile0 all parts -> buf0; tile1 B parts -> buf1
    stB0(0);
    stB1(0);
    stA0(0);
    stA1(0);
    if (nt > 1) {
        stB0(1);
        stB1(1);
        asm volatile("s_waitcnt vmcnt(4)" ::: "memory");  // tile0 landed; B(1) in flight
    } else {
        asm volatile("s_waitcnt vmcnt(0)" ::: "memory");
    }
    __builtin_amdgcn_s_barrier();

    f32x4 acc[NMF][4] = {};
    bf16x8 breg[4][2];

    for (int k = 0; k < nt; ++k) {
        int buf = k & 1, nbuf = buf ^ 1;
        int ao = AOF(buf, wm), bo = BOF(buf, wn >> 1);
        int brow0 = (wn & 1) * 64;
        bool s1 = (k + 1 < nt), s2 = (k + 2 < nt);
        {  // phase 0: read all B + A-quad0; stage A0(k+1)
            AREAD(0)
#pragma unroll
            for (int ni = 0; ni < 4; ni++)
#pragma unroll
                for (int kb = 0; kb < 2; kb++) {
                    int rl = brow0 + ni * 16 + la;
                    breg[ni][kb] = *(const bf16x8*)&lds[bo + rl * 64 +
                                                        (((kb * 4 + lk4) ^ (rl & 7)) << 3)];
                }
            if (s1) stA0(nbuf);
            CLUSTER(0)
            __builtin_amdgcn_s_barrier();
        }
        {  // phase 1: A-quad1; stage A1(k+1)
            AREAD(1)
            if (s1) stA1(nbuf);
            CLUSTER(1)
            __builtin_amdgcn_s_barrier();
        }
        {  // phase 2: A-quad2; stage B0(k+2) into current buf's dead B0 slot
            AREAD(2)
            if (s2) stB0(buf);
            CLUSTER(2)
            __builtin_amdgcn_s_barrier();
        }
        {  // phase 3: A-quad3; stage B1(k+2); counted boundary wait BEFORE barrier
            AREAD(3)
            if (s2) stB1(buf);
            CLUSTER(3)
            if (s2)
                asm volatile("s_waitcnt vmcnt(4)" ::: "memory");
            else
                asm volatile("s_waitcnt vmcnt(0)" ::: "memory");
            __builtin_amdgcn_s_barrier();
        }
    }
#pragma unroll
    for (int mi = 0; mi < NMF; mi++)
#pragma unroll
        for (int ni = 0; ni < 4; ni++)
#pragma unroll
            for (int r_ = 0; r_ < 4; r_++) {
                int m = tm + wm * WTM + mi * 16 + ((lane >> 4) << 2) + r_;
                int n = tn + wn * 64 + ni * 16 + la;
                if (m < M && n < N)
                    Cb[(size_t)m * ldc + n] = f2bf(acc[mi][ni][r_] * alpha);
            }
}

// ---------------- NT GEMM (m97 1-phase, 128 tile) for small GEMMs + fallback ----------------
template <typename OUT>
__global__ __launch_bounds__(256) void gemm_nt128(
    const u16* __restrict__ A, long sAb, long sAh, int lda,
    const u16* __restrict__ B, long sBb, long sBh, int ldb,
    OUT* __restrict__ C, long sCb, long sCh, int ldc,
    int M, int N, int K, int hdiv, float alpha) {
    __shared__ u16 sA[128 * 64];
    __shared__ u16 sB[128 * 64];
    int gx = gridDim.x, gy = gridDim.y;
    int nwg = gx * gy * gridDim.z;
    int orig = blockIdx.x + gx * (blockIdx.y + gy * blockIdx.z);
    int q = nwg >> 3, r = nwg & 7;
    int xcd = orig & 7, seq = orig >> 3;
    int wg = (xcd < r ? xcd * (q + 1) : r * (q + 1) + (xcd - r) * q) + seq;
    int bx = wg % gx, tmpw = wg / gx;
    int by = tmpw % gy, bz = tmpw / gy;

    int bb = bz / hdiv, hh = bz - bb * hdiv;
    const u16* Ab = A + (size_t)bb * sAb + (size_t)hh * sAh;
    const u16* Bb = B + (size_t)bb * sBb + (size_t)hh * sBh;
    OUT* Cb = C + (size_t)bb * sCb + (size_t)hh * sCh;
    int tm = by * 128, tn = bx * 128;
    int t = threadIdx.x, lane = t & 63, w = t >> 6;
    int wr = w >> 1, wc = w & 1;
    int r0 = t >> 3, c0 = (t & 7) * 8;
    const u16* gA[4];
    const u16* gB[4];
#pragma unroll
    for (int i = 0; i < 4; i++) {
        int ar = tm + i * 32 + r0;
        if (ar > M - 1) ar = M - 1;
        gA[i] = Ab + (size_t)ar * lda + c0;
    }
#pragma unroll
    for (int i = 0; i < 4; i++) {
        int br = tn + i * 32 + r0;
        if (br > N - 1) br = N - 1;
        gB[i] = Bb + (size_t)br * ldb + c0;
    }
    f32x4 acc[4][4] = {};
    int la = lane & 15, lk = (lane >> 4) * 8;
    for (int k0 = 0; k0 < K; k0 += 64) {
#pragma unroll
        for (int i = 0; i < 4; i++) {
            gload16(gA[i], &sA[(i * 256 + t) * 8]);
            gA[i] += 64;
        }
#pragma unroll
        for (int i = 0; i < 4; i++) {
            gload16(gB[i], &sB[(i * 256 + t) * 8]);
            gB[i] += 64;
        }
        __syncthreads();
#pragma unroll
        for (int kk = 0; kk < 64; kk += 32) {
            bf16x8 a[4], b[4];
#pragma unroll
            for (int mi = 0; mi < 4; mi++)
                a[mi] = *(const bf16x8*)&sA[(wr * 64 + mi * 16 + la) * 64 + kk + lk];
#pragma unroll
            for (int ni = 0; ni < 4; ni++)
                b[ni] = *(const bf16x8*)&sB[(wc * 64 + ni * 16 + la) * 64 + kk + lk];
#pragma unroll
            for (int mi = 0; mi < 4; mi++)
#pragma unroll
                for (int ni = 0; ni < 4; ni++)
                    acc[mi][ni] = __builtin_amdgcn_mfma_f32_16x16x32_bf16(
                        a[mi], b[ni], acc[mi][ni], 0, 0, 0);
        }
        __syncthreads();
    }
#pragma unroll
    for (int mi = 0; mi < 4; mi++)
#pragma unroll
        for (int ni = 0; ni < 4; ni++)
#pragma unroll
            for (int r_ = 0; r_ < 4; r_++) {
                int m = tm + wr * 64 + mi * 16 + (lane >> 4) * 4 + r_;
                int n = tn + wc * 64 + ni * 16 + la;
                if (m < M && n < N) {
                    float v = acc[mi][ni][r_] * alpha;
                    if constexpr (sizeof(OUT) == 4)
                        Cb[(size_t)m * ldc + n] = v;
                    else
                        Cb[(size_t)m * ldc + n] = f2bf(v);
                }
            }
}

// ---------------- instance-norm stats, stage 1 (bf16 input, two-stage deterministic) ----------------
__global__ __launch_bounds__(256) void in_stats1(const u16* __restrict__ sc,
                                                 double* __restrict__ part,
                                                 int G, int mode, int C) {
    int p = blockIdx.y, g = blockIdx.x, t = threadIdx.x;
    size_t base;
    int n8;
    if (mode) {
        int z = p >> 2, i = p & 3;
        base = (size_t)z * 921600 + (size_t)d_offs[i] * 960;
        n8 = d_cs[i] * 120;
    } else {
        base = (size_t)p * C * 960;
        n8 = C * 120;
    }
    const u16* x = sc + base;
    double s = 0.0, q = 0.0;
    for (int i = g * 256 + t; i < n8; i += G * 256) {
        u16x4 a = *(const u16x4*)&x[i * 8];
        u16x4 b = *(const u16x4*)&x[i * 8 + 4];
#pragma unroll
        for (int j = 0; j < 4; j++) {
            float fa = bf2f(a[j]), fb = bf2f(b[j]);
            s += (double)fa + (double)fb;
            q += (double)fa * fa + (double)fb * fb;
        }
    }
#pragma unroll
    for (int o = 32; o; o >>= 1) {
        s += __shfl_down(s, o);
        q += __shfl_down(q, o);
    }
    __shared__ double rs[4], rq[4];
    int w = t >> 6;
    if ((t & 63) == 0) {
        rs[w] = s;
        rq[w] = q;
    }
    __syncthreads();
    if (t == 0) {
        part[2 * ((size_t)p * G + g)] = rs[0] + rs[1] + rs[2] + rs[3];
        part[2 * ((size_t)p * G + g) + 1] = rq[0] + rq[1] + rq[2] + rq[3];
    }
}

// ---------------- stage 2: reduce G partials per plane -> mu, rsqrt(var+eps) ----------------
__global__ __launch_bounds__(64) void in_stats2(const double* __restrict__ part,
                                                float* __restrict__ stats,
                                                int G, int mode, int C) {
    int p = blockIdx.x, t = threadIdx.x;
    int cnt = (mode ? d_cs[p & 3] : C) * 960;
    double s = 0.0, q = 0.0;
    if (t < G) {
        s = part[2 * ((size_t)p * G + t)];
        q = part[2 * ((size_t)p * G + t) + 1];
    }
#pragma unroll
    for (int o = 32; o; o >>= 1) {
        s += __shfl_down(s, o);
        q += __shfl_down(q, o);
    }
    if (t == 0) {
        float mu = (float)(s / cnt);
        float var = (float)(q / cnt) - mu * mu;
        stats[2 * p] = mu;
        stats[2 * p + 1] = rsqrtf(var + 1e-5f);
    }
}

// ---------------- normalize + softmax -> prCat[b][c][h*960+k] (batched path) ----------------
__global__ __launch_bounds__(256) void norm_softmax_cat(const u16* __restrict__ sc,
                                                        const float* __restrict__ stats,
                                                        u16* __restrict__ prB) {
    int row = blockIdx.x;  // [0, 32*960): z*960 + c
    int z = row / 960, c = row - z * 960;
    int i = c < 512 ? 0 : (c < 768 ? 1 : (c < 896 ? 2 : 3));
    int plane = z * 4 + i;
    int b = z >> 2, h = z & 3;
    const u16* x = sc + (size_t)row * 960;
    u16* o = prB + (((size_t)b * 960 + c) * 4 + h) * 960;
    float mu = stats[2 * plane], rs = stats[2 * plane + 1];
    int t = threadIdx.x;
    bool act = t < 240;
    float v[4];
    float mx = -1e30f;
    if (act) {
        u16x4 d = *(const u16x4*)&x[t * 4];
#pragma unroll
        for (int j = 0; j < 4; j++) {
            v[j] = (bf2f(d[j]) - mu) * rs;
            mx = fmaxf(mx, v[j]);
        }
    }
    __shared__ float r1[4], r2[4];
#pragma unroll
    for (int o_ = 32; o_; o_ >>= 1) mx = fmaxf(mx, __shfl_xor(mx, o_));
    int w = t >> 6;
    if ((t & 63) == 0) r1[w] = mx;
    __syncthreads();
    mx = fmaxf(fmaxf(r1[0], r1[1]), fmaxf(r1[2], r1[3]));
    float s = 0.f;
    if (act) {
#pragma unroll
        for (int j = 0; j < 4; j++) {
            v[j] = __expf(v[j] - mx);
            s += v[j];
        }
    }
#pragma unroll
    for (int o_ = 32; o_; o_ >>= 1) s += __shfl_xor(s, o_);
    if ((t & 63) == 0) r2[w] = s;
    __syncthreads();
    s = r2[0] + r2[1] + r2[2] + r2[3];
    float inv = 1.0f / s;
    if (act) {
        u16x4 ov;
#pragma unroll
        for (int j = 0; j < 4; j++) ov[j] = f2bf(v[j] * inv);
        *(u16x4*)&o[t * 4] = ov;
    }
}

// ---------------- normalize + softmax, in-place (fallback path) ----------------
__global__ __launch_bounds__(256) void norm_softmax_ip(u16* sc,
                                                       const float* __restrict__ stats,
                                                       int C) {
    int row = blockIdx.x;
    int plane = row / C;
    u16* x = sc + (size_t)row * 960;
    float mu = stats[2 * plane], rs = stats[2 * plane + 1];
    int t = threadIdx.x;
    bool act = t < 240;
    float v[4];
    float mx = -1e30f;
    if (act) {
        u16x4 d = *(const u16x4*)&x[t * 4];
#pragma unroll
        for (int j = 0; j < 4; j++) {
            v[j] = (bf2f(d[j]) - mu) * rs;
            mx = fmaxf(mx, v[j]);
        }
    }
    __shared__ float r1[4], r2[4];
#pragma unroll
    for (int o = 32; o; o >>= 1) mx = fmaxf(mx, __shfl_xor(mx, o));
    int w = t >> 6;
    if ((t & 63) == 0) r1[w] = mx;
    __syncthreads();
    mx = fmaxf(fmaxf(r1[0], r1[1]), fmaxf(r1[2], r1[3]));
    float s = 0.f;
    if (act) {
#pragma unroll
        for (int j = 0; j < 4; j++) {
            v[j] = __expf(v[j] - mx);
            s += v[j];
        }
    }
#pragma unroll
    for (int o = 32; o; o >>= 1) s += __shfl_xor(s, o);
    if ((t & 63) == 0) r2[w] = s;
    __syncthreads();
    s = r2[0] + r2[1] + r2[2] + r2[3];
    float inv = 1.0f / s;
    if (act) {
        u16x4 o;
#pragma unroll
        for (int j = 0; j < 4; j++) o[j] = f2bf(v[j] * inv);
        *(u16x4*)&x[t * 4] = o;
    }
}

// ---------------- head-mean + transpose (fallback path only) ----------------
__global__ __launch_bounds__(256) void mean_heads(const u16* __restrict__ ctx, long ps,
                                                  u16* __restrict__ cm, int C) {
    int b = blockIdx.z;
    int n0 = blockIdx.x * 64, c0 = blockIdx.y * 64;
    __shared__ float sm[64][65];
    int t = threadIdx.x;
    float acc[16];
#pragma unroll
    for (int j = 0; j < 16; j++) acc[j] = 0.f;
    for (int h = 0; h < 4; h++) {
        const u16* p = ctx + (size_t)(b * 4 + h) * ps;
#pragma unroll
        for (int j = 0; j < 16; j++) {
            int lin = j * 256 + t;
            int cc = lin >> 6, nn = lin & 63;
            acc[j] += bf2f(p[(size_t)(c0 + cc) * 1024 + n0 + nn]);
        }
    }
#pragma unroll
    for (int j = 0; j < 16; j++) {
        int lin = j * 256 + t;
        sm[lin >> 6][lin & 63] = acc[j] * 0.25f;
    }
    __syncthreads();
#pragma unroll
    for (int j = 0; j < 16; j++) {
        int lin = j * 256 + t;
        int nn = lin >> 6, cc = lin & 63;
        cm[((size_t)b * 1024 + n0 + nn) * C + c0 + cc] = f2bf(sm[cc][nn]);
    }
}

extern "C" void kernel_launch(void* const* d_in, const int* in_sizes, int n_in,
                              void* d_out, int out_size, void* d_ws, size_t ws_size,
                              hipStream_t stream) {
    const int B = 8, NN = 1024, KV = 960;
    const int Cs[4] = {64, 128, 256, 512};   // input order
    const int ord[4] = {3, 2, 1, 0};         // process 512,256,128,64 for row-concat
    const int offs[4] = {0, 512, 768, 896};  // row offset of ord[j] in the 960 space
    const float* emb[4];
    for (int i = 0; i < 4; i++) emb[i] = (const float*)d_in[i];
    const float* embAll = (const float*)d_in[4];
    const float* Wq[4];
    for (int i = 0; i < 4; i++) Wq[i] = (const float*)d_in[5 + i];
    const float* Wk = (const float*)d_in[9];
    const float* Wv = (const float*)d_in[10];
    const float* Wo[4];
    for (int i = 0; i < 4; i++) Wo[i] = (const float*)d_in[11 + i];
    float* out = (float*)d_out;
    size_t outOff[4];
    {
        size_t o = 0;
        for (int i = 0; i < 4; i++) { outOff[i] = o; o += (size_t)B * NN * Cs[i]; }
    }

    const size_t SKV = 62914560;  // 32*960*1024 bf16 (fits VbCat 8*1024*3840, prCat 8*960*3840)
    const size_t SSC = 58982400;  // scores bf16 32*960*960
    const size_t SWQ = 2785280, SWO = 696320, SCM = 8388608;
    const size_t SPART = 131072, SST = 1024;
    const size_t SMALL = SWQ + SWO + SCM + SPART + SST;
    const size_t NEED_BAT = SSC + 3 * SKV + SMALL + 512;

    float invs = 1.0f / sqrtf((float)KV);
    auto g128 = [](int n) { return (n + 127) / 128; };

    if (ws_size >= NEED_BAT) {
        // ================= batched path =================
        char* p = (char*)d_ws;
        u16* scB = (u16*)p;        p += SSC;  // init: eA/wk/wv; then scores bf16; then cmCat
        u16* QtB = (u16*)p;        p += SKV;  // Qt_all [z][960][1024]; then prCat [b][960c][3840]
        u16* Kt = (u16*)p;         p += SKV;  // [z][960 j][1024 n]
        u16* VbC = (u16*)p;        p += SKV;  // VbCat [b][1024 n][3840 hk]
        u16* wq[4];
        for (int i = 0; i < 4; i++) { wq[i] = (u16*)p; p += (size_t)4 * Cs[i] * Cs[i] * 2; }
        u16* wo[4];
        for (int i = 0; i < 4; i++) { wo[i] = (u16*)p; p += (size_t)Cs[i] * Cs[i] * 2; }
        u16* cmX = (u16*)p;        p += SCM;
        double* part = (double*)p; p += SPART;
        float* stats = (float*)p;

        u16* eA = scB;
        u16* wk = (u16*)((char*)scB + 15728640);
        u16* wv = (u16*)((char*)scB + 23101440);
        u16* prB = QtB;  // alias: QtB dead after QK
        u16* cmC = scB;  // alias: scB dead after softmax

        auto castL = [&](const float* s, u16* d, size_t n) {
            int n4 = (int)(n / 4);
            cast_bf16<<<(n4 + 255) / 256, 256, 0, stream>>>((const float4*)s, (u16x4*)d, n4);
        };
        castL(embAll, eA, (size_t)B * NN * KV);
        castL(Wk, wk, (size_t)4 * KV * KV);
        castL(Wv, wv, (size_t)4 * KV * KV);
        for (int i = 0; i < 4; i++) castL(Wq[i], wq[i], (size_t)4 * Cs[i] * Cs[i]);
        for (int i = 0; i < 4; i++) castL(Wo[i], wo[i], (size_t)Cs[i] * Cs[i]);

        // Kt[z][j][n]  (8-phase 256^2)
        gemm_nt_8ph<256><<<dim3(4, 4, 32), 512, 0, stream>>>(
            wk, 0, (long)KV * KV, KV, eA, (long)NN * KV, 0, KV,
            Kt, 4 * 983040L, 983040L, NN, KV, NN, KV, 4, 1.0f);
        // VbCat[b][n][h*960+j]  (8-phase 256^2)
        gemm_nt_8ph<256><<<dim3(4, 4, 32), 512, 0, stream>>>(
            eA, (long)NN * KV, 0, KV, wv, 0, (long)KV * KV, KV,
            VbC, (long)NN * 3840, 960L, 3840, NN, KV, KV, 4, 1.0f);

        // Q-proj all branches into concatenated QtB rows (small GEMMs, 1-phase 128^2)
        for (int j = 0; j < 4; j++) {
            int i = ord[j], C = Cs[i];
            castL(emb[i], cmX, (size_t)B * NN * C);
            gemm_nt128<u16><<<dim3(8, g128(C), 32), 256, 0, stream>>>(
                wq[i], 0, (long)C * C, C, cmX, (long)NN * C, 0, C,
                QtB + (size_t)offs[j] * 1024, 4 * 983040L, 983040L, NN,
                C, NN, C, 4, 1.0f);
        }
        // one big QK: scB[z][960 c][960 k] bf16  (8-phase 256^2)
        gemm_nt_8ph<256><<<dim3(4, 4, 32), 512, 0, stream>>>(
            QtB, 983040L, 0, NN, Kt, 983040L, 0, NN,
            scB, 921600L, 0, KV, 960, KV, NN, 1, invs);
        // instance-norm stats (128 planes) + softmax -> prCat
        in_stats1<<<dim3(16, 128), 256, 0, stream>>>(scB, part, 16, 1, 0);
        in_stats2<<<128, 64, 0, stream>>>(part, stats, 16, 1, 0);
        norm_softmax_cat<<<32 * 960, 256, 0, stream>>>(scB, stats, prB);
        // fused PV + head-mean (8-phase, BM=128 -> 256 blocks):
        // cmC[b][n][960 c] = 0.25 * sum_{hk} VbC[b][n][hk] * prB[b][c][hk]
        gemm_nt_8ph<128><<<dim3(4, 8, 8), 512, 0, stream>>>(
            VbC, (long)NN * 3840, 0, 3840, prB, (long)960 * 3840, 0, 3840,
            cmC, (long)NN * 960, 0, 960, NN, 960, 3840, 1, 0.25f);
        // out-proj per branch
        for (int j = 0; j < 4; j++) {
            int i = ord[j], C = Cs[i];
            gemm_nt128<float><<<dim3(g128(C), 8, 8), 256, 0, stream>>>(
                cmC + offs[j], (long)NN * 960, 0, 960, wo[i], 0, 0, C,
                out + outOff[i], (long)NN * C, 0, C, NN, C, C, 1, 1.0f);
        }
    } else {
        // ================= fallback per-branch path (~205 MB) =================
        const size_t S1 = 33554432, S2 = 33554432;
        if (ws_size < S1 + S2 + 2 * SKV + SMALL + 512) return;
        char* p = (char*)d_ws;
        char* buf1 = p;            p += S1;
        char* buf2 = p;            p += S2;
        u16* Kt = (u16*)p;         p += SKV;
        u16* Vb = (u16*)p;         p += SKV;
        u16* wq[4];
        for (int i = 0; i < 4; i++) { wq[i] = (u16*)p; p += (size_t)4 * Cs[i] * Cs[i] * 2; }
        u16* wo[4];
        for (int i = 0; i < 4; i++) { wo[i] = (u16*)p; p += (size_t)Cs[i] * Cs[i] * 2; }
        u16* cmX = (u16*)p;        p += SCM;
        double* part = (double*)p; p += SPART;
        float* stats = (float*)p;

        u16* eA = (u16*)buf1;
        u16* wk = (u16*)(buf1 + 15728640);
        u16* wv = (u16*)(buf1 + 23101440);
        u16* sc = (u16*)buf1;
        u16* Qt = (u16*)buf2;
        u16* ctx = (u16*)buf2;

        auto castL = [&](const float* s, u16* d, size_t n) {
            int n4 = (int)(n / 4);
            cast_bf16<<<(n4 + 255) / 256, 256, 0, stream>>>((const float4*)s, (u16x4*)d, n4);
        };
        castL(embAll, eA, (size_t)B * NN * KV);
        castL(Wk, wk, (size_t)4 * KV * KV);
        castL(Wv, wv, (size_t)4 * KV * KV);
        for (int i = 0; i < 4; i++) castL(Wq[i], wq[i], (size_t)4 * Cs[i] * Cs[i]);
        for (int i = 0; i < 4; i++) castL(Wo[i], wo[i], (size_t)Cs[i] * Cs[i]);

        gemm_nt128<u16><<<dim3(8, 8, 32), 256, 0, stream>>>(
            wk, 0, (long)KV * KV, KV, eA, (long)NN * KV, 0, KV,
            Kt, 4 * 983040L, 983040L, NN, KV, NN, KV, 4, 1.0f);
        gemm_nt128<u16><<<dim3(8, 8, 32), 256, 0, stream>>>(
            eA, (long)NN * KV, 0, KV, wv, 0, (long)KV * KV, KV,
            Vb, 4 * 983040L, 983040L, KV, NN, KV, KV, 4, 1.0f);

        for (int i = 0; i < 4; i++) {
            int C = Cs[i];
            castL(emb[i], cmX, (size_t)B * NN * C);
            gemm_nt128<u16><<<dim3(8, g128(C), 32), 256, 0, stream>>>(
                wq[i], 0, (long)C * C, C, cmX, (long)NN * C, 0, C,
                Qt, 4L * C * NN, (long)C * NN, NN, C, NN, C, 4, 1.0f);
            gemm_nt128<u16><<<dim3(8, g128(C), 32), 256, 0, stream>>>(
                Qt, (long)C * NN, 0, NN, Kt, 983040L, 0, NN,
                sc, (long)C * KV, 0, KV, C, KV, NN, 1, invs);
            in_stats1<<<dim3(64, 32), 256, 0, stream>>>(sc, part, 64, 0, C);
            in_stats2<<<32, 64, 0, stream>>>(part, stats, 64, 0, C);
            norm_softmax_ip<<<32 * C, 256, 0, stream>>>(sc, stats, C);
            gemm_nt128<u16><<<dim3(8, g128(C), 32), 256, 0, stream>>>(
                sc, (long)C * KV, 0, KV, Vb, 983040L, 0, KV,
                ctx, (long)C * NN, 0, NN, C, NN, KV, 1, 1.0f);
            mean_heads<<<dim3(16, C / 64, B), 256, 0, stream>>>(
                ctx, (long)C * NN, cmX, C);
            gemm_nt128<float><<<dim3(g128(C), 8, B), 256, 0, stream>>>(
                cmX, (long)NN * C, 0, C, wo[i], 0, 0, C,
                out + outOff[i], (long)NN * C, 0, C, NN, C, C, 1, 1.0f);
        }
    }
}

// Round 9
// 459.880 us; speedup vs baseline: 2.4688x; 1.0485x over previous
//
#include <hip/hip_runtime.h>
#include <stdint.h>

typedef unsigned short u16;
typedef short bf16x8 __attribute__((ext_vector_type(8)));
typedef float f32x4 __attribute__((ext_vector_type(4)));
typedef u16 u16x4 __attribute__((ext_vector_type(4)));

__device__ __forceinline__ u16 f2bf(float f) {
    unsigned u = __builtin_bit_cast(unsigned, f);
    unsigned r = (u + 0x7fffu + ((u >> 16) & 1u)) >> 16;
    return (u16)r;
}
__device__ __forceinline__ float bf2f(u16 h) {
    unsigned u = ((unsigned)h) << 16;
    return __builtin_bit_cast(float, u);
}

typedef const __attribute__((address_space(1))) unsigned int* gptr_t;
typedef __attribute__((address_space(3))) unsigned int* lptr_t;
__device__ __forceinline__ void gload16(const void* g, void* l) {
    __builtin_amdgcn_global_load_lds((gptr_t)(uintptr_t)g, (lptr_t)(uintptr_t)l, 16, 0, 0);
}

// branch tables: rows of the concatenated 960-row score/Q space
__device__ __constant__ int d_offs[4] = {0, 512, 768, 896};
__device__ __constant__ int d_cs[4] = {512, 256, 128, 64};

// ---------------- cast f32 -> bf16 (vectorized) ----------------
__global__ __launch_bounds__(256) void cast_bf16(const float4* __restrict__ in,
                                                 u16x4* __restrict__ out, int n4) {
    int i = blockIdx.x * 256 + threadIdx.x;
    if (i < n4) {
        float4 f = in[i];
        u16x4 o = {f2bf(f.x), f2bf(f.y), f2bf(f.z), f2bf(f.w)};
        out[i] = o;
    }
}

// ======== 8-phase counted-vmcnt NT GEMM (m201-style, T2 swizzle, T5) ========
// Round-9 change: single START-of-phase barrier per phase (was 2/phase).
// Hazard audit: wave reaches phase-p barrier only after its p-1 MFMA (after its
// lgkmcnt(0)) => all waves' p0 B-reads complete before any wave's p2/p3 stB*.
// Tile boundary: vmcnt(4) by every wave THEN one barrier (publishes all DMA).
#define AREAD(P)                                                                   \
    bf16x8 areg[MFP][2];                                                           \
    _Pragma("unroll") for (int f = 0; f < MFP; f++)                                \
        _Pragma("unroll") for (int kb = 0; kb < 2; kb++) {                         \
            int rl = ((P)*MFP + f) * 16 + la;                                      \
            areg[f][kb] = *(const bf16x8*)&lds[ao + rl * 64 +                      \
                                               (((kb * 4 + lk4) ^ (rl & 7)) << 3)]; \
        }
#define CLUSTER(P)                                                                 \
    __builtin_amdgcn_s_barrier();                                                  \
    asm volatile("s_waitcnt lgkmcnt(0)" ::: "memory");                             \
    __builtin_amdgcn_sched_barrier(0);                                             \
    __builtin_amdgcn_s_setprio(1);                                                 \
    _Pragma("unroll") for (int f = 0; f < MFP; f++)                                \
        _Pragma("unroll") for (int ni = 0; ni < 4; ni++)                           \
            _Pragma("unroll") for (int kb = 0; kb < 2; kb++)                       \
                acc[(P)*MFP + f][ni] = __builtin_amdgcn_mfma_f32_16x16x32_bf16(    \
                    areg[f][kb], breg[ni][kb], acc[(P)*MFP + f][ni], 0, 0, 0);     \
    __builtin_amdgcn_s_setprio(0);

template <int BM>
__global__ __launch_bounds__(512, 2) void gemm_nt_8ph(
    const u16* __restrict__ A, long sAb, long sAh, int lda,
    const u16* __restrict__ B, long sBb, long sBh, int ldb,
    u16* __restrict__ C, long sCb, long sCh, int ldc,
    int M, int N, int K, int hdiv, float alpha) {
    constexpr int NA = BM / 128;     // gload_lds per thread per A-half stage
    constexpr int MFP = BM / 128;    // m-frags per phase
    constexpr int WTM = BM / 2;      // per-wave rows
    constexpr int NMF = WTM / 16;    // m-frags per wave
    constexpr int APART = WTM * 64;  // u16 per A half
    constexpr int BPART = 128 * 64;
    constexpr int BUFSZ = 2 * APART + 2 * BPART;
    __shared__ u16 lds[2 * BUFSZ];

    // bijective XCD swizzle (m204)
    int gx = gridDim.x, gy = gridDim.y;
    int nwg = gx * gy * gridDim.z;
    int orig = blockIdx.x + gx * (blockIdx.y + gy * blockIdx.z);
    int q = nwg >> 3, r = nwg & 7;
    int xcd = orig & 7, seq = orig >> 3;
    int wg = (xcd < r ? xcd * (q + 1) : r * (q + 1) + (xcd - r) * q) + seq;
    int bx = wg % gx, tmpw = wg / gx;
    int by = tmpw % gy, bz = tmpw / gy;

    int bb = bz / hdiv, hh = bz - bb * hdiv;
    const u16* Ab = A + (size_t)bb * sAb + (size_t)hh * sAh;
    const u16* Bb = B + (size_t)bb * sBb + (size_t)hh * sBh;
    u16* Cb = C + (size_t)bb * sCb + (size_t)hh * sCh;
    int tm = by * BM, tn = bx * 256;
    int t = threadIdx.x, lane = t & 63, w = t >> 6;
    int wm = w >> 2, wn = w & 3;
    int la = lane & 15, lk4 = lane >> 4;

    // staging source pointers: inverse-swizzled col, clamped rows; +=64/tile
    const u16* pA0[NA];
    const u16* pA1[NA];
    const u16* pB0[2];
    const u16* pB1[2];
#pragma unroll
    for (int i = 0; i < NA; i++) {
        int seg = i * 512 + t;
        int col = (((seg & 7) ^ ((seg >> 3) & 7)) << 3);
        int r0 = tm + (seg >> 3);
        if (r0 > M - 1) r0 = M - 1;
        pA0[i] = Ab + (size_t)r0 * lda + col;
        int r1 = tm + WTM + (seg >> 3);
        if (r1 > M - 1) r1 = M - 1;
        pA1[i] = Ab + (size_t)r1 * lda + col;
    }
#pragma unroll
    for (int i = 0; i < 2; i++) {
        int seg = i * 512 + t;
        int col = (((seg & 7) ^ ((seg >> 3) & 7)) << 3);
        int r0 = tn + (seg >> 3);
        if (r0 > N - 1) r0 = N - 1;
        pB0[i] = Bb + (size_t)r0 * ldb + col;
        int r1 = tn + 128 + (seg >> 3);
        if (r1 > N - 1) r1 = N - 1;
        pB1[i] = Bb + (size_t)r1 * ldb + col;
    }

    auto AOF = [&](int buf, int h) { return buf * BUFSZ + h * APART; };
    auto BOF = [&](int buf, int h) { return buf * BUFSZ + 2 * APART + h * BPART; };
    auto stA0 = [&](int buf) {
#pragma unroll
        for (int i = 0; i < NA; i++) {
            gload16(pA0[i], &lds[AOF(buf, 0) + (i * 512 + t) * 8]);
            pA0[i] += 64;
        }
    };
    auto stA1 = [&](int buf) {
#pragma unroll
        for (int i = 0; i < NA; i++) {
            gload16(pA1[i], &lds[AOF(buf, 1) + (i * 512 + t) * 8]);
            pA1[i] += 64;
        }
    };
    auto stB0 = [&](int buf) {
#pragma unroll
        for (int i = 0; i < 2; i++) {
            gload16(pB0[i], &lds[BOF(buf, 0) + (i * 512 + t) * 8]);
            pB0[i] += 64;
        }
    };
    auto stB1 = [&](int buf) {
#pragma unroll
        for (int i = 0; i < 2; i++) {
            gload16(pB1[i], &lds[BOF(buf, 1) + (i * 512 + t) * 8]);
            pB1[i] += 64;
        }
    };

    int nt = K / 64;
    // prologue: tile0 all parts -> buf0; tile1 B parts -> buf1
    stB0(0);
    stB1(0);
    stA0(0);
    stA1(0);
    if (nt > 1) {
        stB0(1);
        stB1(1);
        asm volatile("s_waitcnt vmcnt(4)" ::: "memory");  // tile0 landed; B(1) in flight
    } else {
        asm volatile("s_waitcnt vmcnt(0)" ::: "memory");
    }
    __builtin_amdgcn_s_barrier();

    f32x4 acc[NMF][4] = {};
    bf16x8 breg[4][2];

    for (int k = 0; k < nt; ++k) {
        int buf = k & 1, nbuf = buf ^ 1;
        int ao = AOF(buf, wm), bo = BOF(buf, wn >> 1);
        int brow0 = (wn & 1) * 64;
        bool s1 = (k + 1 < nt), s2 = (k + 2 < nt);
        {  // phase 0: read all B + A-quad0; stage A0(k+1)
            AREAD(0)
#pragma unroll
            for (int ni = 0; ni < 4; ni++)
#pragma unroll
                for (int kb = 0; kb < 2; kb++) {
                    int rl = brow0 + ni * 16 + la;
                    breg[ni][kb] = *(const bf16x8*)&lds[bo + rl * 64 +
                                                        (((kb * 4 + lk4) ^ (rl & 7)) << 3)];
                }
            if (s1) stA0(nbuf);
            CLUSTER(0)
        }
        {  // phase 1: A-quad1; stage A1(k+1)
            AREAD(1)
            if (s1) stA1(nbuf);
            CLUSTER(1)
        }
        {  // phase 2: A-quad2; stage B0(k+2) into current buf's dead B0 slot
            AREAD(2)
            if (s2) stB0(buf);
            CLUSTER(2)
        }
        {  // phase 3: A-quad3; stage B1(k+2); counted boundary wait + publish barrier
            AREAD(3)
            if (s2) stB1(buf);
            CLUSTER(3)
            if (s2)
                asm volatile("s_waitcnt vmcnt(4)" ::: "memory");
            else
                asm volatile("s_waitcnt vmcnt(0)" ::: "memory");
            __builtin_amdgcn_s_barrier();  // publish all waves' DMA for buf[k+1]
        }
    }
#pragma unroll
    for (int mi = 0; mi < NMF; mi++)
#pragma unroll
        for (int ni = 0; ni < 4; ni++)
#pragma unroll
            for (int r_ = 0; r_ < 4; r_++) {
                int m = tm + wm * WTM + mi * 16 + ((lane >> 4) << 2) + r_;
                int n = tn + wn * 64 + ni * 16 + la;
                if (m < M && n < N)
                    Cb[(size_t)m * ldc + n] = f2bf(acc[mi][ni][r_] * alpha);
            }
}

// ---------------- NT GEMM (m97 1-phase, 128 tile) for small GEMMs + fallback ----------------
template <typename OUT>
__global__ __launch_bounds__(256) void gemm_nt128(
    const u16* __restrict__ A, long sAb, long sAh, int lda,
    const u16* __restrict__ B, long sBb, long sBh, int ldb,
    OUT* __restrict__ C, long sCb, long sCh, int ldc,
    int M, int N, int K, int hdiv, float alpha) {
    __shared__ u16 sA[128 * 64];
    __shared__ u16 sB[128 * 64];
    int gx = gridDim.x, gy = gridDim.y;
    int nwg = gx * gy * gridDim.z;
    int orig = blockIdx.x + gx * (blockIdx.y + gy * blockIdx.z);
    int q = nwg >> 3, r = nwg & 7;
    int xcd = orig & 7, seq = orig >> 3;
    int wg = (xcd < r ? xcd * (q + 1) : r * (q + 1) + (xcd - r) * q) + seq;
    int bx = wg % gx, tmpw = wg / gx;
    int by = tmpw % gy, bz = tmpw / gy;

    int bb = bz / hdiv, hh = bz - bb * hdiv;
    const u16* Ab = A + (size_t)bb * sAb + (size_t)hh * sAh;
    const u16* Bb = B + (size_t)bb * sBb + (size_t)hh * sBh;
    OUT* Cb = C + (size_t)bb * sCb + (size_t)hh * sCh;
    int tm = by * 128, tn = bx * 128;
    int t = threadIdx.x, lane = t & 63, w = t >> 6;
    int wr = w >> 1, wc = w & 1;
    int r0 = t >> 3, c0 = (t & 7) * 8;
    const u16* gA[4];
    const u16* gB[4];
#pragma unroll
    for (int i = 0; i < 4; i++) {
        int ar = tm + i * 32 + r0;
        if (ar > M - 1) ar = M - 1;
        gA[i] = Ab + (size_t)ar * lda + c0;
    }
#pragma unroll
    for (int i = 0; i < 4; i++) {
        int br = tn + i * 32 + r0;
        if (br > N - 1) br = N - 1;
        gB[i] = Bb + (size_t)br * ldb + c0;
    }
    f32x4 acc[4][4] = {};
    int la = lane & 15, lk = (lane >> 4) * 8;
    for (int k0 = 0; k0 < K; k0 += 64) {
#pragma unroll
        for (int i = 0; i < 4; i++) {
            gload16(gA[i], &sA[(i * 256 + t) * 8]);
            gA[i] += 64;
        }
#pragma unroll
        for (int i = 0; i < 4; i++) {
            gload16(gB[i], &sB[(i * 256 + t) * 8]);
            gB[i] += 64;
        }
        __syncthreads();
#pragma unroll
        for (int kk = 0; kk < 64; kk += 32) {
            bf16x8 a[4], b[4];
#pragma unroll
            for (int mi = 0; mi < 4; mi++)
                a[mi] = *(const bf16x8*)&sA[(wr * 64 + mi * 16 + la) * 64 + kk + lk];
#pragma unroll
            for (int ni = 0; ni < 4; ni++)
                b[ni] = *(const bf16x8*)&sB[(wc * 64 + ni * 16 + la) * 64 + kk + lk];
#pragma unroll
            for (int mi = 0; mi < 4; mi++)
#pragma unroll
                for (int ni = 0; ni < 4; ni++)
                    acc[mi][ni] = __builtin_amdgcn_mfma_f32_16x16x32_bf16(
                        a[mi], b[ni], acc[mi][ni], 0, 0, 0);
        }
        __syncthreads();
    }
#pragma unroll
    for (int mi = 0; mi < 4; mi++)
#pragma unroll
        for (int ni = 0; ni < 4; ni++)
#pragma unroll
            for (int r_ = 0; r_ < 4; r_++) {
                int m = tm + wr * 64 + mi * 16 + (lane >> 4) * 4 + r_;
                int n = tn + wc * 64 + ni * 16 + la;
                if (m < M && n < N) {
                    float v = acc[mi][ni][r_] * alpha;
                    if constexpr (sizeof(OUT) == 4)
                        Cb[(size_t)m * ldc + n] = v;
                    else
                        Cb[(size_t)m * ldc + n] = f2bf(v);
                }
            }
}

// ---------------- instance-norm stats, stage 1 (bf16 input, two-stage deterministic) ----------------
__global__ __launch_bounds__(256) void in_stats1(const u16* __restrict__ sc,
                                                 double* __restrict__ part,
                                                 int G, int mode, int C) {
    int p = blockIdx.y, g = blockIdx.x, t = threadIdx.x;
    size_t base;
    int n8;
    if (mode) {
        int z = p >> 2, i = p & 3;
        base = (size_t)z * 921600 + (size_t)d_offs[i] * 960;
        n8 = d_cs[i] * 120;
    } else {
        base = (size_t)p * C * 960;
        n8 = C * 120;
    }
    const u16* x = sc + base;
    double s = 0.0, q = 0.0;
    for (int i = g * 256 + t; i < n8; i += G * 256) {
        u16x4 a = *(const u16x4*)&x[i * 8];
        u16x4 b = *(const u16x4*)&x[i * 8 + 4];
#pragma unroll
        for (int j = 0; j < 4; j++) {
            float fa = bf2f(a[j]), fb = bf2f(b[j]);
            s += (double)fa + (double)fb;
            q += (double)fa * fa + (double)fb * fb;
        }
    }
#pragma unroll
    for (int o = 32; o; o >>= 1) {
        s += __shfl_down(s, o);
        q += __shfl_down(q, o);
    }
    __shared__ double rs[4], rq[4];
    int w = t >> 6;
    if ((t & 63) == 0) {
        rs[w] = s;
        rq[w] = q;
    }
    __syncthreads();
    if (t == 0) {
        part[2 * ((size_t)p * G + g)] = rs[0] + rs[1] + rs[2] + rs[3];
        part[2 * ((size_t)p * G + g) + 1] = rq[0] + rq[1] + rq[2] + rq[3];
    }
}

// ---------------- stage 2: reduce G partials per plane -> mu, rsqrt(var+eps) ----------------
__global__ __launch_bounds__(64) void in_stats2(const double* __restrict__ part,
                                                float* __restrict__ stats,
                                                int G, int mode, int C) {
    int p = blockIdx.x, t = threadIdx.x;
    int cnt = (mode ? d_cs[p & 3] : C) * 960;
    double s = 0.0, q = 0.0;
    if (t < G) {
        s = part[2 * ((size_t)p * G + t)];
        q = part[2 * ((size_t)p * G + t) + 1];
    }
#pragma unroll
    for (int o = 32; o; o >>= 1) {
        s += __shfl_down(s, o);
        q += __shfl_down(q, o);
    }
    if (t == 0) {
        float mu = (float)(s / cnt);
        float var = (float)(q / cnt) - mu * mu;
        stats[2 * p] = mu;
        stats[2 * p + 1] = rsqrtf(var + 1e-5f);
    }
}

// ---------------- normalize + softmax -> prCat[b][c][h*960+k] (batched path) ----------------
__global__ __launch_bounds__(256) void norm_softmax_cat(const u16* __restrict__ sc,
                                                        const float* __restrict__ stats,
                                                        u16* __restrict__ prB) {
    int row = blockIdx.x;  // [0, 32*960): z*960 + c
    int z = row / 960, c = row - z * 960;
    int i = c < 512 ? 0 : (c < 768 ? 1 : (c < 896 ? 2 : 3));
    int plane = z * 4 + i;
    int b = z >> 2, h = z & 3;
    const u16* x = sc + (size_t)row * 960;
    u16* o = prB + (((size_t)b * 960 + c) * 4 + h) * 960;
    float mu = stats[2 * plane], rs = stats[2 * plane + 1];
    int t = threadIdx.x;
    bool act = t < 240;
    float v[4];
    float mx = -1e30f;
    if (act) {
        u16x4 d = *(const u16x4*)&x[t * 4];
#pragma unroll
        for (int j = 0; j < 4; j++) {
            v[j] = (bf2f(d[j]) - mu) * rs;
            mx = fmaxf(mx, v[j]);
        }
    }
    __shared__ float r1[4], r2[4];
#pragma unroll
    for (int o_ = 32; o_; o_ >>= 1) mx = fmaxf(mx, __shfl_xor(mx, o_));
    int w = t >> 6;
    if ((t & 63) == 0) r1[w] = mx;
    __syncthreads();
    mx = fmaxf(fmaxf(r1[0], r1[1]), fmaxf(r1[2], r1[3]));
    float s = 0.f;
    if (act) {
#pragma unroll
        for (int j = 0; j < 4; j++) {
            v[j] = __expf(v[j] - mx);
            s += v[j];
        }
    }
#pragma unroll
    for (int o_ = 32; o_; o_ >>= 1) s += __shfl_xor(s, o_);
    if ((t & 63) == 0) r2[w] = s;
    __syncthreads();
    s = r2[0] + r2[1] + r2[2] + r2[3];
    float inv = 1.0f / s;
    if (act) {
        u16x4 ov;
#pragma unroll
        for (int j = 0; j < 4; j++) ov[j] = f2bf(v[j] * inv);
        *(u16x4*)&o[t * 4] = ov;
    }
}

// ---------------- normalize + softmax, in-place (fallback path) ----------------
__global__ __launch_bounds__(256) void norm_softmax_ip(u16* sc,
                                                       const float* __restrict__ stats,
                                                       int C) {
    int row = blockIdx.x;
    int plane = row / C;
    u16* x = sc + (size_t)row * 960;
    float mu = stats[2 * plane], rs = stats[2 * plane + 1];
    int t = threadIdx.x;
    bool act = t < 240;
    float v[4];
    float mx = -1e30f;
    if (act) {
        u16x4 d = *(const u16x4*)&x[t * 4];
#pragma unroll
        for (int j = 0; j < 4; j++) {
            v[j] = (bf2f(d[j]) - mu) * rs;
            mx = fmaxf(mx, v[j]);
        }
    }
    __shared__ float r1[4], r2[4];
#pragma unroll
    for (int o = 32; o; o >>= 1) mx = fmaxf(mx, __shfl_xor(mx, o));
    int w = t >> 6;
    if ((t & 63) == 0) r1[w] = mx;
    __syncthreads();
    mx = fmaxf(fmaxf(r1[0], r1[1]), fmaxf(r1[2], r1[3]));
    float s = 0.f;
    if (act) {
#pragma unroll
        for (int j = 0; j < 4; j++) {
            v[j] = __expf(v[j] - mx);
            s += v[j];
        }
    }
#pragma unroll
    for (int o = 32; o; o >>= 1) s += __shfl_xor(s, o);
    if ((t & 63) == 0) r2[w] = s;
    __syncthreads();
    s = r2[0] + r2[1] + r2[2] + r2[3];
    float inv = 1.0f / s;
    if (act) {
        u16x4 o;
#pragma unroll
        for (int j = 0; j < 4; j++) o[j] = f2bf(v[j] * inv);
        *(u16x4*)&x[t * 4] = o;
    }
}

// ---------------- head-mean + transpose (fallback path only) ----------------
__global__ __launch_bounds__(256) void mean_heads(const u16* __restrict__ ctx, long ps,
                                                  u16* __restrict__ cm, int C) {
    int b = blockIdx.z;
    int n0 = blockIdx.x * 64, c0 = blockIdx.y * 64;
    __shared__ float sm[64][65];
    int t = threadIdx.x;
    float acc[16];
#pragma unroll
    for (int j = 0; j < 16; j++) acc[j] = 0.f;
    for (int h = 0; h < 4; h++) {
        const u16* p = ctx + (size_t)(b * 4 + h) * ps;
#pragma unroll
        for (int j = 0; j < 16; j++) {
            int lin = j * 256 + t;
            int cc = lin >> 6, nn = lin & 63;
            acc[j] += bf2f(p[(size_t)(c0 + cc) * 1024 + n0 + nn]);
        }
    }
#pragma unroll
    for (int j = 0; j < 16; j++) {
        int lin = j * 256 + t;
        sm[lin >> 6][lin & 63] = acc[j] * 0.25f;
    }
    __syncthreads();
#pragma unroll
    for (int j = 0; j < 16; j++) {
        int lin = j * 256 + t;
        int nn = lin >> 6, cc = lin & 63;
        cm[((size_t)b * 1024 + n0 + nn) * C + c0 + cc] = f2bf(sm[cc][nn]);
    }
}

extern "C" void kernel_launch(void* const* d_in, const int* in_sizes, int n_in,
                              void* d_out, int out_size, void* d_ws, size_t ws_size,
                              hipStream_t stream) {
    const int B = 8, NN = 1024, KV = 960;
    const int Cs[4] = {64, 128, 256, 512};   // input order
    const int ord[4] = {3, 2, 1, 0};         // process 512,256,128,64 for row-concat
    const int offs[4] = {0, 512, 768, 896};  // row offset of ord[j] in the 960 space
    const float* emb[4];
    for (int i = 0; i < 4; i++) emb[i] = (const float*)d_in[i];
    const float* embAll = (const float*)d_in[4];
    const float* Wq[4];
    for (int i = 0; i < 4; i++) Wq[i] = (const float*)d_in[5 + i];
    const float* Wk = (const float*)d_in[9];
    const float* Wv = (const float*)d_in[10];
    const float* Wo[4];
    for (int i = 0; i < 4; i++) Wo[i] = (const float*)d_in[11 + i];
    float* out = (float*)d_out;
    size_t outOff[4];
    {
        size_t o = 0;
        for (int i = 0; i < 4; i++) { outOff[i] = o; o += (size_t)B * NN * Cs[i]; }
    }

    const size_t SKV = 62914560;  // 32*960*1024 bf16 (fits VbCat 8*1024*3840, prCat 8*960*3840)
    const size_t SSC = 58982400;  // scores bf16 32*960*960
    const size_t SWQ = 2785280, SWO = 696320, SCM = 8388608;
    const size_t SPART = 131072, SST = 1024;
    const size_t SMALL = SWQ + SWO + SCM + SPART + SST;
    const size_t NEED_BAT = SSC + 3 * SKV + SMALL + 512;

    float invs = 1.0f / sqrtf((float)KV);
    auto g128 = [](int n) { return (n + 127) / 128; };

    if (ws_size >= NEED_BAT) {
        // ================= batched path =================
        char* p = (char*)d_ws;
        u16* scB = (u16*)p;        p += SSC;  // init: eA/wk/wv; then scores bf16; then cmCat
        u16* QtB = (u16*)p;        p += SKV;  // Qt_all [z][960][1024]; then prCat [b][960c][3840]
        u16* Kt = (u16*)p;         p += SKV;  // [z][960 j][1024 n]
        u16* VbC = (u16*)p;        p += SKV;  // VbCat [b][1024 n][3840 hk]
        u16* wq[4];
        for (int i = 0; i < 4; i++) { wq[i] = (u16*)p; p += (size_t)4 * Cs[i] * Cs[i] * 2; }
        u16* wo[4];
        for (int i = 0; i < 4; i++) { wo[i] = (u16*)p; p += (size_t)Cs[i] * Cs[i] * 2; }
        u16* cmX = (u16*)p;        p += SCM;
        double* part = (double*)p; p += SPART;
        float* stats = (float*)p;

        u16* eA = scB;
        u16* wk = (u16*)((char*)scB + 15728640);
        u16* wv = (u16*)((char*)scB + 23101440);
        u16* prB = QtB;  // alias: QtB dead after QK
        u16* cmC = scB;  // alias: scB dead after softmax

        auto castL = [&](const float* s, u16* d, size_t n) {
            int n4 = (int)(n / 4);
            cast_bf16<<<(n4 + 255) / 256, 256, 0, stream>>>((const float4*)s, (u16x4*)d, n4);
        };
        castL(embAll, eA, (size_t)B * NN * KV);
        castL(Wk, wk, (size_t)4 * KV * KV);
        castL(Wv, wv, (size_t)4 * KV * KV);
        for (int i = 0; i < 4; i++) castL(Wq[i], wq[i], (size_t)4 * Cs[i] * Cs[i]);
        for (int i = 0; i < 4; i++) castL(Wo[i], wo[i], (size_t)Cs[i] * Cs[i]);

        // Kt[z][j][n]  (8-phase 256^2)
        gemm_nt_8ph<256><<<dim3(4, 4, 32), 512, 0, stream>>>(
            wk, 0, (long)KV * KV, KV, eA, (long)NN * KV, 0, KV,
            Kt, 4 * 983040L, 983040L, NN, KV, NN, KV, 4, 1.0f);
        // VbCat[b][n][h*960+j]  (8-phase 256^2)
        gemm_nt_8ph<256><<<dim3(4, 4, 32), 512, 0, stream>>>(
            eA, (long)NN * KV, 0, KV, wv, 0, (long)KV * KV, KV,
            VbC, (long)NN * 3840, 960L, 3840, NN, KV, KV, 4, 1.0f);

        // Q-proj: C=512 on 8ph (256 blocks), smaller C on 1-phase 128^2
        for (int j = 0; j < 4; j++) {
            int i = ord[j], C = Cs[i];
            castL(emb[i], cmX, (size_t)B * NN * C);
            if (C == 512) {
                gemm_nt_8ph<256><<<dim3(4, 2, 32), 512, 0, stream>>>(
                    wq[i], 0, (long)C * C, C, cmX, (long)NN * C, 0, C,
                    QtB + (size_t)offs[j] * 1024, 4 * 983040L, 983040L, NN,
                    C, NN, C, 4, 1.0f);
            } else {
                gemm_nt128<u16><<<dim3(8, g128(C), 32), 256, 0, stream>>>(
                    wq[i], 0, (long)C * C, C, cmX, (long)NN * C, 0, C,
                    QtB + (size_t)offs[j] * 1024, 4 * 983040L, 983040L, NN,
                    C, NN, C, 4, 1.0f);
            }
        }
        // one big QK: scB[z][960 c][960 k] bf16  (8-phase 256^2)
        gemm_nt_8ph<256><<<dim3(4, 4, 32), 512, 0, stream>>>(
            QtB, 983040L, 0, NN, Kt, 983040L, 0, NN,
            scB, 921600L, 0, KV, 960, KV, NN, 1, invs);
        // instance-norm stats (128 planes) + softmax -> prCat
        in_stats1<<<dim3(16, 128), 256, 0, stream>>>(scB, part, 16, 1, 0);
        in_stats2<<<128, 64, 0, stream>>>(part, stats, 16, 1, 0);
        norm_softmax_cat<<<32 * 960, 256, 0, stream>>>(scB, stats, prB);
        // fused PV + head-mean (8-phase, BM=128 -> 256 blocks):
        // cmC[b][n][960 c] = 0.25 * sum_{hk} VbC[b][n][hk] * prB[b][c][hk]
        gemm_nt_8ph<128><<<dim3(4, 8, 8), 512, 0, stream>>>(
            VbC, (long)NN * 3840, 0, 3840, prB, (long)960 * 3840, 0, 3840,
            cmC, (long)NN * 960, 0, 960, NN, 960, 3840, 1, 0.25f);
        // out-proj per branch
        for (int j = 0; j < 4; j++) {
            int i = ord[j], C = Cs[i];
            gemm_nt128<float><<<dim3(g128(C), 8, 8), 256, 0, stream>>>(
                cmC + offs[j], (long)NN * 960, 0, 960, wo[i], 0, 0, C,
                out + outOff[i], (long)NN * C, 0, C, NN, C, C, 1, 1.0f);
        }
    } else {
        // ================= fallback per-branch path (~205 MB) =================
        const size_t S1 = 33554432, S2 = 33554432;
        if (ws_size < S1 + S2 + 2 * SKV + SMALL + 512) return;
        char* p = (char*)d_ws;
        char* buf1 = p;            p += S1;
        char* buf2 = p;            p += S2;
        u16* Kt = (u16*)p;         p += SKV;
        u16* Vb = (u16*)p;         p += SKV;
        u16* wq[4];
        for (int i = 0; i < 4; i++) { wq[i] = (u16*)p; p += (size_t)4 * Cs[i] * Cs[i] * 2; }
        u16* wo[4];
        for (int i = 0; i < 4; i++) { wo[i] = (u16*)p; p += (size_t)Cs[i] * Cs[i] * 2; }
        u16* cmX = (u16*)p;        p += SCM;
        double* part = (double*)p; p += SPART;
        float* stats = (float*)p;

        u16* eA = (u16*)buf1;
        u16* wk = (u16*)(buf1 + 15728640);
        u16* wv = (u16*)(buf1 + 23101440);
        u16* sc = (u16*)buf1;
        u16* Qt = (u16*)buf2;
        u16* ctx = (u16*)buf2;

        auto castL = [&](const float* s, u16* d, size_t n) {
            int n4 = (int)(n / 4);
            cast_bf16<<<(n4 + 255) / 256, 256, 0, stream>>>((const float4*)s, (u16x4*)d, n4);
        };
        castL(embAll, eA, (size_t)B * NN * KV);
        castL(Wk, wk, (size_t)4 * KV * KV);
        castL(Wv, wv, (size_t)4 * KV * KV);
        for (int i = 0; i < 4; i++) castL(Wq[i], wq[i], (size_t)4 * Cs[i] * Cs[i]);
        for (int i = 0; i < 4; i++) castL(Wo[i], wo[i], (size_t)Cs[i] * Cs[i]);

        gemm_nt128<u16><<<dim3(8, 8, 32), 256, 0, stream>>>(
            wk, 0, (long)KV * KV, KV, eA, (long)NN * KV, 0, KV,
            Kt, 4 * 983040L, 983040L, NN, KV, NN, KV, 4, 1.0f);
        gemm_nt128<u16><<<dim3(8, 8, 32), 256, 0, stream>>>(
            eA, (long)NN * KV, 0, KV, wv, 0, (long)KV * KV, KV,
            Vb, 4 * 983040L, 983040L, KV, NN, KV, KV, 4, 1.0f);

        for (int i = 0; i < 4; i++) {
            int C = Cs[i];
            castL(emb[i], cmX, (size_t)B * NN * C);
            gemm_nt128<u16><<<dim3(8, g128(C), 32), 256, 0, stream>>>(
                wq[i], 0, (long)C * C, C, cmX, (long)NN * C, 0, C,
                Qt, 4L * C * NN, (long)C * NN, NN, C, NN, C, 4, 1.0f);
            gemm_nt128<u16><<<dim3(8, g128(C), 32), 256, 0, stream>>>(
                Qt, (long)C * NN, 0, NN, Kt, 983040L, 0, NN,
                sc, (long)C * KV, 0, KV, C, KV, NN, 1, invs);
            in_stats1<<<dim3(64, 32), 256, 0, stream>>>(sc, part, 64, 0, C);
            in_stats2<<<32, 64, 0, stream>>>(part, stats, 64, 0, C);
            norm_softmax_ip<<<32 * C, 256, 0, stream>>>(sc, stats, C);
            gemm_nt128<u16><<<dim3(8, g128(C), 32), 256, 0, stream>>>(
                sc, (long)C * KV, 0, KV, Vb, 983040L, 0, KV,
                ctx, (long)C * NN, 0, NN, C, NN, KV, 1, 1.0f);
            mean_heads<<<dim3(16, C / 64, B), 256, 0, stream>>>(
                ctx, (long)C * NN, cmX, C);
            gemm_nt128<float><<<dim3(g128(C), 8, B), 256, 0, stream>>>(
                cmX, (long)NN * C, 0, C, wo[i], 0, 0, C,
                out + outOff[i], (long)NN * C, 0, C, NN, C, C, 1, 1.0f);
        }
    }
}